// Round 1
// baseline (1140.615 us; speedup 1.0000x reference)
//
#include <hip/hip_runtime.h>
#include <math.h>

#define N_NODES 102400
#define N_EDGES 1638400

// ---------------- degrees ----------------
__global__ void deg_kernel(const int* __restrict__ src, const int* __restrict__ dst,
                           float* __restrict__ outdeg, float* __restrict__ indeg, int E) {
    int i = blockIdx.x * blockDim.x + threadIdx.x;
    if (i < E) {
        atomicAdd(outdeg + src[i], 1.0f);
        atomicAdd(indeg + dst[i], 1.0f);
    }
}

// a[i] = 1/sqrt(max(a[i],1))  over both degree arrays (contiguous 2N)
__global__ void invsqrt_kernel(float* __restrict__ a, int n) {
    int i = blockIdx.x * blockDim.x + threadIdx.x;
    if (i < n) {
        float v = a[i];
        v = v < 1.0f ? 1.0f : v;
        a[i] = 1.0f / sqrtf(v);
    }
}

// ---------------- node transform: out[row][c] = (sum_k h[row][k]*W[k][c]) * scale[row]
template<int K, int C>
__global__ void gemm_scale_kernel(const float* __restrict__ h, const float* __restrict__ W,
                                  const float* __restrict__ scale, float* __restrict__ out,
                                  int M) {
    __shared__ float Ws[K * C];
    for (int i = threadIdx.x; i < K * C; i += blockDim.x) Ws[i] = W[i];
    __syncthreads();

    constexpr int ROWS = 256 / C;
    int col = threadIdx.x % C;
    int row = blockIdx.x * ROWS + threadIdx.x / C;
    if (row >= M) return;

    const float* hr = h + (long)row * K;
    float acc = 0.0f;
#pragma unroll
    for (int k = 0; k < K; ++k) acc += hr[k] * Ws[k * C + col];
    out[(long)row * C + col] = acc * scale[row];
}

// ---------------- edge scatter: agg[dst[e]][c] += ht[src[e]][c] * ew[e]
template<int C>
__global__ void scatter_kernel(const float* __restrict__ ht, const int* __restrict__ src,
                               const int* __restrict__ dst, const float* __restrict__ ew,
                               float* __restrict__ agg, int E) {
    int lane = threadIdx.x % C;
    int group = (blockIdx.x * blockDim.x + threadIdx.x) / C;
    int ngroups = (gridDim.x * blockDim.x) / C;
    for (int e = group; e < E; e += ngroups) {
        int s = src[e];
        int d = dst[e];
        float w = ew[e];
        float v = ht[(long)s * C + lane] * w;
        atomicAdd(agg + (long)d * C + lane, v);
    }
}

// ---------------- finalize: out[n][c] = act(agg[n][c] * indeg_inv[n] + b[c])
template<int C, bool TANH>
__global__ void finalize_kernel(const float* __restrict__ agg, const float* __restrict__ indeg_inv,
                                const float* __restrict__ bias, float* __restrict__ out, int M) {
    int i = blockIdx.x * blockDim.x + threadIdx.x;
    if (i < M * C) {
        int n = i / C;
        int c = i % C;
        float v = agg[i] * indeg_inv[n] + bias[c];
        out[i] = TANH ? tanhf(v) : v;
    }
}

extern "C" void kernel_launch(void* const* d_in, const int* in_sizes, int n_in,
                              void* d_out, int out_size, void* d_ws, size_t ws_size,
                              hipStream_t stream) {
    const float* b_z = (const float*)d_in[0];
    const int*   src = (const int*)d_in[1];
    const int*   dst = (const int*)d_in[2];
    const float* ew  = (const float*)d_in[3];
    // d_in[4] = b_size (scalar) — only affects reshape; output is flat identical
    const float* W0 = (const float*)d_in[5];
    const float* b0 = (const float*)d_in[6];
    const float* W1 = (const float*)d_in[7];
    const float* b1 = (const float*)d_in[8];
    const float* W2 = (const float*)d_in[9];
    const float* b2 = (const float*)d_in[10];
    float* out = (float*)d_out;

    const int N = N_NODES;
    const int E = N_EDGES;

    // workspace layout (floats)
    float* ws = (float*)d_ws;
    float* outdeg = ws;             // N   (then holds outdeg^-1/2)
    float* indeg  = ws + N;         // N   (then holds indeg^-1/2)
    float* bufA   = ws + 2L * N;        // N*64  (ht)
    float* agg    = ws + 2L * N + 64L * N;  // N*64
    float* bufB   = ws + 2L * N + 128L * N; // N*64  (h between layers)

    // ---- degrees (ws is poisoned every call: zero first) ----
    hipMemsetAsync(outdeg, 0, 2L * N * sizeof(float), stream);
    deg_kernel<<<(E + 255) / 256, 256, 0, stream>>>(src, dst, outdeg, indeg, E);
    invsqrt_kernel<<<(2 * N + 255) / 256, 256, 0, stream>>>(outdeg, 2 * N);

    const int SC_BLOCKS = 8192;

    // ---- layer 0: 128 -> 64, tanh ----
    gemm_scale_kernel<128, 64><<<N / 4, 256, 0, stream>>>(b_z, W0, outdeg, bufA, N);
    hipMemsetAsync(agg, 0, 64L * N * sizeof(float), stream);
    scatter_kernel<64><<<SC_BLOCKS, 256, 0, stream>>>(bufA, src, dst, ew, agg, E);
    finalize_kernel<64, true><<<(N * 64) / 256, 256, 0, stream>>>(agg, indeg, b0, bufB, N);

    // ---- layer 1: 64 -> 32, tanh ----
    gemm_scale_kernel<64, 32><<<N / 8, 256, 0, stream>>>(bufB, W1, outdeg, bufA, N);
    hipMemsetAsync(agg, 0, 32L * N * sizeof(float), stream);
    scatter_kernel<32><<<SC_BLOCKS, 256, 0, stream>>>(bufA, src, dst, ew, agg, E);
    finalize_kernel<32, true><<<(N * 32) / 256, 256, 0, stream>>>(agg, indeg, b1, bufB, N);

    // ---- layer 2: 32 -> 1, no activation, straight to d_out ----
    gemm_scale_kernel<32, 1><<<N / 256, 256, 0, stream>>>(bufB, W2, outdeg, bufA, N);
    hipMemsetAsync(agg, 0, 1L * N * sizeof(float), stream);
    scatter_kernel<1><<<SC_BLOCKS, 256, 0, stream>>>(bufA, src, dst, ew, agg, E);
    finalize_kernel<1, false><<<N / 256, 256, 0, stream>>>(agg, indeg, b2, out, N);
}

// Round 3
// 922.545 us; speedup vs baseline: 1.2364x; 1.2364x over previous
//
#include <hip/hip_runtime.h>
#include <math.h>

#define N_NODES 102400
#define N_EDGES 1638400

// ---------------- degree counts (int) ----------------
__global__ void deg_kernel(const int* __restrict__ src, const int* __restrict__ dst,
                           int* __restrict__ cnt_out, int* __restrict__ cnt_in, int E) {
    int i = blockIdx.x * blockDim.x + threadIdx.x;
    if (i < E) {
        atomicAdd(cnt_out + src[i], 1);
        atomicAdd(cnt_in + dst[i], 1);
    }
}

// outdeg_inv[i] = rsqrt(max(cnt_out,1)); indeg_inv[i] = rsqrt(max(cnt_in,1))
__global__ void invsqrt_kernel(const int* __restrict__ cnt_out, const int* __restrict__ cnt_in,
                               float* __restrict__ outdeg_inv, float* __restrict__ indeg_inv, int n) {
    int i = blockIdx.x * blockDim.x + threadIdx.x;
    if (i < n) {
        float a = (float)max(cnt_out[i], 1);
        float b = (float)max(cnt_in[i], 1);
        outdeg_inv[i] = 1.0f / sqrtf(a);
        indeg_inv[i]  = 1.0f / sqrtf(b);
    }
}

// ---------------- single-block exclusive scan of cnt_in -> row_off, row_off[n]=total ----
__global__ __launch_bounds__(1024) void scan_kernel(const int* __restrict__ cnt, int* __restrict__ off,
                                                    int n, int total) {
    __shared__ int wave_sums[16];
    __shared__ int carry_s;
    if (threadIdx.x == 0) carry_s = 0;
    __syncthreads();
    int lane = threadIdx.x & 63;
    int wid  = threadIdx.x >> 6;
    for (int base = 0; base < n; base += 1024) {
        int i = base + threadIdx.x;
        int v = (i < n) ? cnt[i] : 0;
        // inclusive wave scan
        int x = v;
        #pragma unroll
        for (int s = 1; s < 64; s <<= 1) {
            int t = __shfl_up(x, s, 64);
            if (lane >= s) x += t;
        }
        if (lane == 63) wave_sums[wid] = x;
        __syncthreads();
        if (wid == 0) {
            int ws = (lane < 16) ? wave_sums[lane] : 0;
            int y = ws;
            #pragma unroll
            for (int s = 1; s < 16; s <<= 1) {
                int t = __shfl_up(y, s, 64);
                if (lane >= s) y += t;
            }
            if (lane < 16) wave_sums[lane] = y - ws;  // exclusive wave offsets
        }
        __syncthreads();
        int excl = carry_s + wave_sums[wid] + (x - v);
        if (i < n) off[i] = excl;
        __syncthreads();
        if (threadIdx.x == 1023) carry_s += wave_sums[15] + x;  // x = inclusive sum of wave 15
        __syncthreads();
    }
    if (threadIdx.x == 0) off[n] = total;
}

// ---------------- CSR fill: permute edges into dst-sorted order ----------------
__global__ void fill_csr_kernel(const int* __restrict__ src, const int* __restrict__ dst,
                                const float* __restrict__ ew, int* __restrict__ cursor,
                                int* __restrict__ src_perm, float* __restrict__ wgt_perm, int E) {
    int i = blockIdx.x * blockDim.x + threadIdx.x;
    if (i < E) {
        int d = dst[i];
        int p = atomicAdd(cursor + d, 1);
        src_perm[p] = src[i];
        wgt_perm[p] = ew[i];
    }
}

// ---------------- node transform: out[row][c] = (h[row] . W[:,c]) * scale[row] ----
template<int K, int C>
__global__ void gemm_scale_kernel(const float* __restrict__ h, const float* __restrict__ W,
                                  const float* __restrict__ scale, float* __restrict__ out,
                                  int M) {
    __shared__ float Ws[K * C];
    for (int i = threadIdx.x; i < K * C; i += blockDim.x) Ws[i] = W[i];
    __syncthreads();

    constexpr int ROWS = 256 / C;
    int col = threadIdx.x % C;
    int row = blockIdx.x * ROWS + threadIdx.x / C;
    if (row >= M) return;

    const float4* hr = (const float4*)(h + (long)row * K);
    float acc = 0.0f;
#pragma unroll
    for (int k4 = 0; k4 < K / 4; ++k4) {
        float4 hv = hr[k4];
        acc += hv.x * Ws[(k4 * 4 + 0) * C + col];
        acc += hv.y * Ws[(k4 * 4 + 1) * C + col];
        acc += hv.z * Ws[(k4 * 4 + 2) * C + col];
        acc += hv.w * Ws[(k4 * 4 + 3) * C + col];
    }
    out[(long)row * C + col] = acc * scale[row];
}

// layer-2 transform K=32 -> 1: wave handles 2 rows (32 lanes each), shuffle-reduce halves.
// 2 rows/wave * 4 waves/block = 8 rows/block -> grid N/8.
__global__ void gemm_scale_k32c1_kernel(const float* __restrict__ h, const float* __restrict__ W,
                                        const float* __restrict__ scale, float* __restrict__ out, int M) {
    __shared__ float Ws[32];
    if (threadIdx.x < 32) Ws[threadIdx.x] = W[threadIdx.x];
    __syncthreads();
    int lane = threadIdx.x & 63;
    int wave = (blockIdx.x * blockDim.x + threadIdx.x) >> 6;
    int c = lane & 31, half = lane >> 5;
    int row = wave * 2 + half;
    if (row >= M) return;
    float v = h[(long)row * 32 + c] * Ws[c];
#pragma unroll
    for (int s = 16; s >= 1; s >>= 1) v += __shfl_xor(v, s, 64);  // stays within 32-lane half
    if (c == 0) out[row] = v * scale[row];
}

// ---------------- CSR aggregation, fused finalize ----------------
// C=64: one wave per node, lane = channel
template<bool TANH>
__global__ void agg64_kernel(const float* __restrict__ ht, const int* __restrict__ row_off,
                             const int* __restrict__ sp, const float* __restrict__ wp,
                             const float* __restrict__ indeg_inv, const float* __restrict__ bias,
                             float* __restrict__ out, int N) {
    int wave = (blockIdx.x * blockDim.x + threadIdx.x) >> 6;
    int lane = threadIdx.x & 63;
    if (wave >= N) return;
    int beg = row_off[wave], end = row_off[wave + 1];
    float acc0 = 0.0f, acc1 = 0.0f;
    int e = beg;
    for (; e + 1 < end; e += 2) {
        int s0 = sp[e], s1 = sp[e + 1];
        float w0 = wp[e], w1 = wp[e + 1];
        acc0 += ht[(long)s0 * 64 + lane] * w0;
        acc1 += ht[(long)s1 * 64 + lane] * w1;
    }
    if (e < end) acc0 += ht[(long)sp[e] * 64 + lane] * wp[e];
    float v = (acc0 + acc1) * indeg_inv[wave] + bias[lane];
    out[(long)wave * 64 + lane] = TANH ? tanhf(v) : v;
}

// C=32: one wave per node; halves process alternating edges, then combine
template<bool TANH>
__global__ void agg32_kernel(const float* __restrict__ ht, const int* __restrict__ row_off,
                             const int* __restrict__ sp, const float* __restrict__ wp,
                             const float* __restrict__ indeg_inv, const float* __restrict__ bias,
                             float* __restrict__ out, int N) {
    int wave = (blockIdx.x * blockDim.x + threadIdx.x) >> 6;
    int lane = threadIdx.x & 63;
    int c = lane & 31, half = lane >> 5;
    if (wave >= N) return;
    int beg = row_off[wave], end = row_off[wave + 1];
    float acc = 0.0f;
    for (int e = beg + half; e < end; e += 2) {
        acc += ht[(long)sp[e] * 32 + c] * wp[e];
    }
    acc += __shfl_xor(acc, 32, 64);
    if (half == 0) {
        float v = acc * indeg_inv[wave] + bias[c];
        out[(long)wave * 32 + c] = TANH ? tanhf(v) : v;
    }
}

// C=1: one thread per node
__global__ void agg1_kernel(const float* __restrict__ ht, const int* __restrict__ row_off,
                            const int* __restrict__ sp, const float* __restrict__ wp,
                            const float* __restrict__ indeg_inv, const float* __restrict__ bias,
                            float* __restrict__ out, int N) {
    int n = blockIdx.x * blockDim.x + threadIdx.x;
    if (n >= N) return;
    int beg = row_off[n], end = row_off[n + 1];
    float acc = 0.0f;
    for (int e = beg; e < end; ++e) acc += ht[sp[e]] * wp[e];
    out[n] = acc * indeg_inv[n] + bias[0];
}

extern "C" void kernel_launch(void* const* d_in, const int* in_sizes, int n_in,
                              void* d_out, int out_size, void* d_ws, size_t ws_size,
                              hipStream_t stream) {
    const float* b_z = (const float*)d_in[0];
    const int*   src = (const int*)d_in[1];
    const int*   dst = (const int*)d_in[2];
    const float* ew  = (const float*)d_in[3];
    const float* W0 = (const float*)d_in[5];
    const float* b0 = (const float*)d_in[6];
    const float* W1 = (const float*)d_in[7];
    const float* b1 = (const float*)d_in[8];
    const float* W2 = (const float*)d_in[9];
    const float* b2 = (const float*)d_in[10];
    float* out = (float*)d_out;

    const int N = N_NODES;
    const int E = N_EDGES;

    // workspace layout
    char* p = (char*)d_ws;
    int*   cnt_out    = (int*)p;            p += (size_t)N * 4;
    int*   cnt_in     = (int*)p;            p += (size_t)N * 4;
    int*   row_off    = (int*)p;            p += (size_t)(N + 1) * 4;
    int*   cursor     = (int*)p;            p += (size_t)N * 4;
    float* outdeg_inv = (float*)p;          p += (size_t)N * 4;
    float* indeg_inv  = (float*)p;          p += (size_t)N * 4;
    int*   src_perm   = (int*)p;            p += (size_t)E * 4;
    float* wgt_perm   = (float*)p;          p += (size_t)E * 4;
    // align to 16B for float4 loads
    p = (char*)(((size_t)p + 15) & ~(size_t)15);
    float* bufA       = (float*)p;          p += (size_t)N * 64 * 4;
    float* bufB       = (float*)p;

    // ---- degree counts (ws poisoned each call: zero first) ----
    hipMemsetAsync(cnt_out, 0, 2L * N * sizeof(int), stream);
    deg_kernel<<<(E + 255) / 256, 256, 0, stream>>>(src, dst, cnt_out, cnt_in, E);
    invsqrt_kernel<<<(N + 255) / 256, 256, 0, stream>>>(cnt_out, cnt_in, outdeg_inv, indeg_inv, N);

    // ---- CSR build ----
    scan_kernel<<<1, 1024, 0, stream>>>(cnt_in, row_off, N, E);
    hipMemcpyAsync(cursor, row_off, (size_t)N * sizeof(int), hipMemcpyDeviceToDevice, stream);
    fill_csr_kernel<<<(E + 255) / 256, 256, 0, stream>>>(src, dst, ew, cursor, src_perm, wgt_perm, E);

    // ---- layer 0: 128 -> 64, tanh ----
    gemm_scale_kernel<128, 64><<<N / 4, 256, 0, stream>>>(b_z, W0, outdeg_inv, bufA, N);
    agg64_kernel<true><<<N / 4, 256, 0, stream>>>(bufA, row_off, src_perm, wgt_perm, indeg_inv, b0, bufB, N);

    // ---- layer 1: 64 -> 32, tanh ----
    gemm_scale_kernel<64, 32><<<N / 8, 256, 0, stream>>>(bufB, W1, outdeg_inv, bufA, N);
    agg32_kernel<true><<<N / 4, 256, 0, stream>>>(bufA, row_off, src_perm, wgt_perm, indeg_inv, b1, bufB, N);

    // ---- layer 2: 32 -> 1, no activation ----
    gemm_scale_k32c1_kernel<<<N / 8, 256, 0, stream>>>(bufB, W2, outdeg_inv, bufA, N);
    agg1_kernel<<<(N + 255) / 256, 256, 0, stream>>>(bufA, row_off, src_perm, wgt_perm, indeg_inv, b2, out, N);
}

// Round 4
// 662.702 us; speedup vs baseline: 1.7212x; 1.3921x over previous
//
#include <hip/hip_runtime.h>
#include <math.h>

#define N_NODES 102400
#define N_EDGES 1638400

// ---------------- degree counts (int) ----------------
__global__ void deg_kernel(const int* __restrict__ src, const int* __restrict__ dst,
                           int* __restrict__ cnt_out, int* __restrict__ cnt_in, int E) {
    int i = blockIdx.x * blockDim.x + threadIdx.x;
    if (i < E) {
        atomicAdd(cnt_out + src[i], 1);
        atomicAdd(cnt_in + dst[i], 1);
    }
}

// outdeg_inv[i] = rsqrt(max(cnt_out,1)); indeg_inv[i] = rsqrt(max(cnt_in,1))
__global__ void invsqrt_kernel(const int* __restrict__ cnt_out, const int* __restrict__ cnt_in,
                               float* __restrict__ outdeg_inv, float* __restrict__ indeg_inv, int n) {
    int i = blockIdx.x * blockDim.x + threadIdx.x;
    if (i < n) {
        float a = (float)max(cnt_out[i], 1);
        float b = (float)max(cnt_in[i], 1);
        outdeg_inv[i] = 1.0f / sqrtf(a);
        indeg_inv[i]  = 1.0f / sqrtf(b);
    }
}

// ---------------- single-block exclusive scan of cnt_in -> row_off, row_off[n]=total ----
__global__ __launch_bounds__(1024) void scan_kernel(const int* __restrict__ cnt, int* __restrict__ off,
                                                    int n, int total) {
    __shared__ int wave_sums[16];
    __shared__ int carry_s;
    if (threadIdx.x == 0) carry_s = 0;
    __syncthreads();
    int lane = threadIdx.x & 63;
    int wid  = threadIdx.x >> 6;
    for (int base = 0; base < n; base += 1024) {
        int i = base + threadIdx.x;
        int v = (i < n) ? cnt[i] : 0;
        int x = v;
        #pragma unroll
        for (int s = 1; s < 64; s <<= 1) {
            int t = __shfl_up(x, s, 64);
            if (lane >= s) x += t;
        }
        if (lane == 63) wave_sums[wid] = x;
        __syncthreads();
        if (wid == 0) {
            int ws = (lane < 16) ? wave_sums[lane] : 0;
            int y = ws;
            #pragma unroll
            for (int s = 1; s < 16; s <<= 1) {
                int t = __shfl_up(y, s, 64);
                if (lane >= s) y += t;
            }
            if (lane < 16) wave_sums[lane] = y - ws;  // exclusive wave offsets
        }
        __syncthreads();
        int excl = carry_s + wave_sums[wid] + (x - v);
        if (i < n) off[i] = excl;
        __syncthreads();
        if (threadIdx.x == 1023) carry_s += wave_sums[15] + x;
        __syncthreads();
    }
    if (threadIdx.x == 0) off[n] = total;
}

// ---------------- CSR fill: permute edges (src,w packed) into dst-sorted order ----------------
__global__ void fill_csr_kernel(const int* __restrict__ src, const int* __restrict__ dst,
                                const float* __restrict__ ew, int* __restrict__ cursor,
                                int2* __restrict__ edge_perm, int E) {
    int i = blockIdx.x * blockDim.x + threadIdx.x;
    if (i < E) {
        int d = dst[i];
        int p = atomicAdd(cursor + d, 1);
        edge_perm[p] = make_int2(src[i], __float_as_int(ew[i]));
    }
}

// ---------------- register-tiled node transform ----------------
// out[row][c] = (h[row] . W[:,c]) * scale[row]
// block: 256 threads = (C/RN) x (64/4); 64 rows/block; K staged in 64-chunks.
template<int K, int C, int RN>
__global__ __launch_bounds__(256) void gemm_tile_kernel(
    const float* __restrict__ h, const float* __restrict__ W,
    const float* __restrict__ scale, float* __restrict__ out) {
    constexpr int BM = 64;
    constexpr int RM = 4;
    constexpr int KC = 64;                   // k-chunk in LDS
    constexpr int TX = C / RN;               // 16
    constexpr int TY = BM / RM;              // 16
    static_assert(TX * TY == 256, "bad tile");

    __shared__ float Ws[K * C];              // full W, row-major [K][C]
    __shared__ float Hs[KC][BM + 4];         // transposed h chunk, pre-scaled; +4 keeps 16B align

    const int tid = threadIdx.x;
    const long brow = (long)blockIdx.x * BM;

    // stage W once
    for (int i = tid; i < K * C; i += 256) Ws[i] = W[i];

    const int tx = tid % TX;
    const int ty = tid / TX;
    float acc[RM][RN] = {};

    // staging map for one 64-wide k-chunk: 16 float4-threads per k-chunk-row
    const int lr = tid % 16;                 // row-within-pass
    const int lk = tid / 16;                 // float4 index 0..15

    for (int kc = 0; kc < K; kc += KC) {
        __syncthreads();                     // protect Hs before overwrite (also covers Ws pass 1)
        #pragma unroll
        for (int p0 = 0; p0 < BM; p0 += 16) {
            const int r = p0 + lr;
            const float s = scale[brow + r];
            const float4 hv = *(const float4*)(h + (brow + r) * K + kc + lk * 4);
            Hs[lk * 4 + 0][r] = hv.x * s;
            Hs[lk * 4 + 1][r] = hv.y * s;
            Hs[lk * 4 + 2][r] = hv.z * s;
            Hs[lk * 4 + 3][r] = hv.w * s;
        }
        __syncthreads();

        #pragma unroll
        for (int k = 0; k < KC; ++k) {
            const float4 a4 = *(const float4*)&Hs[k][ty * RM];
            const float av[RM] = {a4.x, a4.y, a4.z, a4.w};
            float b[RN];
            if constexpr (RN == 4) {
                *(float4*)b = *(const float4*)&Ws[(kc + k) * C + tx * RN];
            } else {
                *(float2*)b = *(const float2*)&Ws[(kc + k) * C + tx * RN];
            }
            #pragma unroll
            for (int i = 0; i < RM; ++i)
                #pragma unroll
                for (int j = 0; j < RN; ++j)
                    acc[i][j] += av[i] * b[j];
        }
    }

    // epilogue: coalesced vector stores
    #pragma unroll
    for (int i = 0; i < RM; ++i) {
        const long row = brow + ty * RM + i;
        if constexpr (RN == 4) {
            float4 v = {acc[i][0], acc[i][1], acc[i][2], acc[i][3]};
            *(float4*)(out + row * C + tx * RN) = v;
        } else {
            float2 v = {acc[i][0], acc[i][1]};
            *(float2*)(out + row * C + tx * RN) = v;
        }
    }
}

// layer-2 transform K=32 -> 1: wave handles 2 rows (32 lanes each); grid N/8
__global__ void gemm_scale_k32c1_kernel(const float* __restrict__ h, const float* __restrict__ W,
                                        const float* __restrict__ scale, float* __restrict__ out, int M) {
    __shared__ float Ws[32];
    if (threadIdx.x < 32) Ws[threadIdx.x] = W[threadIdx.x];
    __syncthreads();
    int lane = threadIdx.x & 63;
    int wave = (blockIdx.x * blockDim.x + threadIdx.x) >> 6;
    int c = lane & 31, half = lane >> 5;
    int row = wave * 2 + half;
    if (row >= M) return;
    float v = h[(long)row * 32 + c] * Ws[c];
#pragma unroll
    for (int s = 16; s >= 1; s >>= 1) v += __shfl_xor(v, s, 64);  // stays within 32-lane half
    if (c == 0) out[row] = v * scale[row];
}

// ---------------- CSR aggregation, fused finalize ----------------
// C=64: one wave per node, lane = channel; 4-deep unroll for MLP
template<bool TANH>
__global__ void agg64_kernel(const float* __restrict__ ht, const int* __restrict__ row_off,
                             const int2* __restrict__ ep,
                             const float* __restrict__ indeg_inv, const float* __restrict__ bias,
                             float* __restrict__ out, int N) {
    int wave = (blockIdx.x * blockDim.x + threadIdx.x) >> 6;
    int lane = threadIdx.x & 63;
    if (wave >= N) return;
    int beg = row_off[wave], end = row_off[wave + 1];
    float acc0 = 0.0f, acc1 = 0.0f, acc2 = 0.0f, acc3 = 0.0f;
    int e = beg;
    for (; e + 3 < end; e += 4) {
        int2 e0 = ep[e], e1 = ep[e + 1], e2 = ep[e + 2], e3 = ep[e + 3];
        acc0 += ht[(long)e0.x * 64 + lane] * __int_as_float(e0.y);
        acc1 += ht[(long)e1.x * 64 + lane] * __int_as_float(e1.y);
        acc2 += ht[(long)e2.x * 64 + lane] * __int_as_float(e2.y);
        acc3 += ht[(long)e3.x * 64 + lane] * __int_as_float(e3.y);
    }
    for (; e < end; ++e) {
        int2 t = ep[e];
        acc0 += ht[(long)t.x * 64 + lane] * __int_as_float(t.y);
    }
    float v = ((acc0 + acc1) + (acc2 + acc3)) * indeg_inv[wave] + bias[lane];
    out[(long)wave * 64 + lane] = TANH ? tanhf(v) : v;
}

// C=32: one wave per node; halves process alternating edges, then combine
template<bool TANH>
__global__ void agg32_kernel(const float* __restrict__ ht, const int* __restrict__ row_off,
                             const int2* __restrict__ ep,
                             const float* __restrict__ indeg_inv, const float* __restrict__ bias,
                             float* __restrict__ out, int N) {
    int wave = (blockIdx.x * blockDim.x + threadIdx.x) >> 6;
    int lane = threadIdx.x & 63;
    int c = lane & 31, half = lane >> 5;
    if (wave >= N) return;
    int beg = row_off[wave], end = row_off[wave + 1];
    float acc0 = 0.0f, acc1 = 0.0f;
    int e = beg + half;
    for (; e + 2 < end; e += 4) {
        int2 t0 = ep[e], t1 = ep[e + 2];
        acc0 += ht[(long)t0.x * 32 + c] * __int_as_float(t0.y);
        acc1 += ht[(long)t1.x * 32 + c] * __int_as_float(t1.y);
    }
    if (e < end) {
        int2 t = ep[e];
        acc0 += ht[(long)t.x * 32 + c] * __int_as_float(t.y);
    }
    float acc = acc0 + acc1;
    acc += __shfl_xor(acc, 32, 64);
    if (half == 0) {
        float v = acc * indeg_inv[wave] + bias[c];
        out[(long)wave * 32 + c] = TANH ? tanhf(v) : v;
    }
}

// C=1: one thread per node
__global__ void agg1_kernel(const float* __restrict__ ht, const int* __restrict__ row_off,
                            const int2* __restrict__ ep,
                            const float* __restrict__ indeg_inv, const float* __restrict__ bias,
                            float* __restrict__ out, int N) {
    int n = blockIdx.x * blockDim.x + threadIdx.x;
    if (n >= N) return;
    int beg = row_off[n], end = row_off[n + 1];
    float acc = 0.0f;
    for (int e = beg; e < end; ++e) {
        int2 t = ep[e];
        acc += ht[t.x] * __int_as_float(t.y);
    }
    out[n] = acc * indeg_inv[n] + bias[0];
}

extern "C" void kernel_launch(void* const* d_in, const int* in_sizes, int n_in,
                              void* d_out, int out_size, void* d_ws, size_t ws_size,
                              hipStream_t stream) {
    const float* b_z = (const float*)d_in[0];
    const int*   src = (const int*)d_in[1];
    const int*   dst = (const int*)d_in[2];
    const float* ew  = (const float*)d_in[3];
    const float* W0 = (const float*)d_in[5];
    const float* b0 = (const float*)d_in[6];
    const float* W1 = (const float*)d_in[7];
    const float* b1 = (const float*)d_in[8];
    const float* W2 = (const float*)d_in[9];
    const float* b2 = (const float*)d_in[10];
    float* out = (float*)d_out;

    const int N = N_NODES;
    const int E = N_EDGES;

    // workspace layout
    char* p = (char*)d_ws;
    int*   cnt_out    = (int*)p;            p += (size_t)N * 4;
    int*   cnt_in     = (int*)p;            p += (size_t)N * 4;
    int*   row_off    = (int*)p;            p += (size_t)(N + 1) * 4;
    int*   cursor     = (int*)p;            p += (size_t)N * 4;
    float* outdeg_inv = (float*)p;          p += (size_t)N * 4;
    float* indeg_inv  = (float*)p;          p += (size_t)N * 4;
    p = (char*)(((size_t)p + 15) & ~(size_t)15);
    int2*  edge_perm  = (int2*)p;           p += (size_t)E * 8;
    float* bufA       = (float*)p;          p += (size_t)N * 64 * 4;
    float* bufB       = (float*)p;

    // ---- degree counts (ws poisoned each call: zero first) ----
    hipMemsetAsync(cnt_out, 0, 2L * N * sizeof(int), stream);
    deg_kernel<<<(E + 255) / 256, 256, 0, stream>>>(src, dst, cnt_out, cnt_in, E);
    invsqrt_kernel<<<(N + 255) / 256, 256, 0, stream>>>(cnt_out, cnt_in, outdeg_inv, indeg_inv, N);

    // ---- CSR build ----
    scan_kernel<<<1, 1024, 0, stream>>>(cnt_in, row_off, N, E);
    hipMemcpyAsync(cursor, row_off, (size_t)N * sizeof(int), hipMemcpyDeviceToDevice, stream);
    fill_csr_kernel<<<(E + 255) / 256, 256, 0, stream>>>(src, dst, ew, cursor, edge_perm, E);

    // ---- layer 0: 128 -> 64, tanh ----
    gemm_tile_kernel<128, 64, 4><<<N / 64, 256, 0, stream>>>(b_z, W0, outdeg_inv, bufA);
    agg64_kernel<true><<<N / 4, 256, 0, stream>>>(bufA, row_off, edge_perm, indeg_inv, b0, bufB, N);

    // ---- layer 1: 64 -> 32, tanh ----
    gemm_tile_kernel<64, 32, 2><<<N / 64, 256, 0, stream>>>(bufB, W1, outdeg_inv, bufA);
    agg32_kernel<true><<<N / 4, 256, 0, stream>>>(bufA, row_off, edge_perm, indeg_inv, b1, bufB, N);

    // ---- layer 2: 32 -> 1, no activation ----
    gemm_scale_k32c1_kernel<<<N / 8, 256, 0, stream>>>(bufB, W2, outdeg_inv, bufA, N);
    agg1_kernel<<<(N + 255) / 256, 256, 0, stream>>>(bufA, row_off, edge_perm, indeg_inv, b2, out, N);
}

// Round 5
// 563.360 us; speedup vs baseline: 2.0247x; 1.1763x over previous
//
#include <hip/hip_runtime.h>
#include <math.h>

#define N_NODES 102400
#define N_EDGES 1638400

// ---------------- degree counts + dst-rank (one atomic pass) ----------------
// rank[i] = position of edge i within its dst bucket (atomic order, nondeterministic but consistent)
__global__ void deg_rank_kernel(const int* __restrict__ src, const int* __restrict__ dst,
                                int* __restrict__ cnt_out, int* __restrict__ cnt_in,
                                int* __restrict__ rank, int E) {
    int i = blockIdx.x * blockDim.x + threadIdx.x;
    if (i < E) {
        atomicAdd(cnt_out + src[i], 1);
        rank[i] = atomicAdd(cnt_in + dst[i], 1);
    }
}

// ---------------- fused: exclusive scan of cnt_in -> row_off; deg^-1/2 arrays ----------------
// single block, 1024 threads, int4 per thread per pass (N/4096 = 25 passes)
__global__ __launch_bounds__(1024) void scan_fused_kernel(
    const int4* __restrict__ cnt_in4, const int4* __restrict__ cnt_out4,
    int* __restrict__ row_off, float* __restrict__ outdeg_inv, float* __restrict__ indeg_inv,
    int n4, int total) {
    __shared__ int wave_sums[16];
    __shared__ int carry_s;
    if (threadIdx.x == 0) carry_s = 0;
    __syncthreads();
    int lane = threadIdx.x & 63;
    int wid  = threadIdx.x >> 6;
    for (int base = 0; base < n4; base += 1024) {
        int i = base + threadIdx.x;           // int4 index
        int4 c = (i < n4) ? cnt_in4[i] : make_int4(0, 0, 0, 0);
        int s0 = c.x, s01 = c.x + c.y, s012 = s01 + c.z;
        int v = s012 + c.w;                   // thread total
        // inclusive wave scan of thread totals
        int x = v;
        #pragma unroll
        for (int s = 1; s < 64; s <<= 1) {
            int t = __shfl_up(x, s, 64);
            if (lane >= s) x += t;
        }
        if (lane == 63) wave_sums[wid] = x;
        __syncthreads();
        if (wid == 0) {
            int ws = (lane < 16) ? wave_sums[lane] : 0;
            int y = ws;
            #pragma unroll
            for (int s = 1; s < 16; s <<= 1) {
                int t = __shfl_up(y, s, 64);
                if (lane >= s) y += t;
            }
            if (lane < 16) wave_sums[lane] = y - ws;   // exclusive wave offsets
        }
        __syncthreads();
        int excl = carry_s + wave_sums[wid] + (x - v);
        if (i < n4) {
            int4 o = make_int4(excl, excl + s0, excl + s01, excl + s012);
            *(int4*)(row_off + 4 * i) = o;
            int4 co = cnt_out4[i];
            float4 oi, ii;
            oi.x = 1.0f / sqrtf((float)max(co.x, 1));
            oi.y = 1.0f / sqrtf((float)max(co.y, 1));
            oi.z = 1.0f / sqrtf((float)max(co.z, 1));
            oi.w = 1.0f / sqrtf((float)max(co.w, 1));
            ii.x = 1.0f / sqrtf((float)max(c.x, 1));
            ii.y = 1.0f / sqrtf((float)max(c.y, 1));
            ii.z = 1.0f / sqrtf((float)max(c.z, 1));
            ii.w = 1.0f / sqrtf((float)max(c.w, 1));
            *(float4*)(outdeg_inv + 4 * i) = oi;
            *(float4*)(indeg_inv + 4 * i) = ii;
        }
        __syncthreads();
        if (threadIdx.x == 1023) carry_s += wave_sums[15] + x;
        __syncthreads();
    }
    if (threadIdx.x == 0) row_off[4 * n4] = total;
}

// ---------------- CSR fill: atomic-free scatter; weight pre-scaled by outdeg_inv[src] ----------------
__global__ void fill_csr_kernel(const int* __restrict__ src, const int* __restrict__ dst,
                                const float* __restrict__ ew, const int* __restrict__ rank,
                                const int* __restrict__ row_off, const float* __restrict__ outdeg_inv,
                                int2* __restrict__ edge_perm, int E) {
    int i = blockIdx.x * blockDim.x + threadIdx.x;
    if (i < E) {
        int s = src[i];
        int p = row_off[dst[i]] + rank[i];
        float w = ew[i] * outdeg_inv[s];
        edge_perm[p] = make_int2(s, __float_as_int(w));
    }
}

// ---------------- register-tiled node transform: out = h @ W (no scale) ----------------
// block: 256 threads; 64 rows/block; K staged in 64-chunks; thread tile RM x RN.
template<int K, int C, int RN>
__global__ __launch_bounds__(256) void gemm_tile_kernel(
    const float* __restrict__ h, const float* __restrict__ W, float* __restrict__ out) {
    constexpr int BM = 64;
    constexpr int RM = 4;
    constexpr int KC = 64;
    constexpr int TX = C / RN;               // 16
    constexpr int TY = BM / RM;              // 16
    static_assert(TX * TY == 256, "bad tile");

    __shared__ float Ws[K * C];              // full W, row-major [K][C]
    __shared__ float Hs[KC][BM + 4];         // transposed h chunk; +4 keeps 16B align

    const int tid = threadIdx.x;
    const long brow = (long)blockIdx.x * BM;

    for (int i = tid; i < K * C; i += 256) Ws[i] = W[i];

    const int tx = tid % TX;
    const int ty = tid / TX;
    float acc[RM][RN] = {};

    const int lr = tid % 16;                 // row-within-pass
    const int lk = tid / 16;                 // float4 index 0..15

    for (int kc = 0; kc < K; kc += KC) {
        __syncthreads();
        #pragma unroll
        for (int p0 = 0; p0 < BM; p0 += 16) {
            const int r = p0 + lr;
            const float4 hv = *(const float4*)(h + (brow + r) * K + kc + lk * 4);
            Hs[lk * 4 + 0][r] = hv.x;
            Hs[lk * 4 + 1][r] = hv.y;
            Hs[lk * 4 + 2][r] = hv.z;
            Hs[lk * 4 + 3][r] = hv.w;
        }
        __syncthreads();

        #pragma unroll
        for (int k = 0; k < KC; ++k) {
            const float4 a4 = *(const float4*)&Hs[k][ty * RM];
            const float av[RM] = {a4.x, a4.y, a4.z, a4.w};
            float b[RN];
            if constexpr (RN == 4) {
                *(float4*)b = *(const float4*)&Ws[(kc + k) * C + tx * RN];
            } else {
                *(float2*)b = *(const float2*)&Ws[(kc + k) * C + tx * RN];
            }
            #pragma unroll
            for (int i = 0; i < RM; ++i)
                #pragma unroll
                for (int j = 0; j < RN; ++j)
                    acc[i][j] += av[i] * b[j];
        }
    }

    #pragma unroll
    for (int i = 0; i < RM; ++i) {
        const long row = brow + ty * RM + i;
        if constexpr (RN == 4) {
            float4 v = {acc[i][0], acc[i][1], acc[i][2], acc[i][3]};
            *(float4*)(out + row * C + tx * RN) = v;
        } else {
            float2 v = {acc[i][0], acc[i][1]};
            *(float2*)(out + row * C + tx * RN) = v;
        }
    }
}

// ---------------- CSR aggregation, fused finalize ----------------
// C=64: one wave per node, lane = channel; 4-deep unroll for MLP
__global__ void agg64_kernel(const float* __restrict__ ht, const int* __restrict__ row_off,
                             const int2* __restrict__ ep,
                             const float* __restrict__ indeg_inv, const float* __restrict__ bias,
                             float* __restrict__ out, int N) {
    int wave = (blockIdx.x * blockDim.x + threadIdx.x) >> 6;
    int lane = threadIdx.x & 63;
    if (wave >= N) return;
    int beg = row_off[wave], end = row_off[wave + 1];
    float acc0 = 0.0f, acc1 = 0.0f, acc2 = 0.0f, acc3 = 0.0f;
    int e = beg;
    for (; e + 3 < end; e += 4) {
        int2 e0 = ep[e], e1 = ep[e + 1], e2 = ep[e + 2], e3 = ep[e + 3];
        acc0 += ht[(long)e0.x * 64 + lane] * __int_as_float(e0.y);
        acc1 += ht[(long)e1.x * 64 + lane] * __int_as_float(e1.y);
        acc2 += ht[(long)e2.x * 64 + lane] * __int_as_float(e2.y);
        acc3 += ht[(long)e3.x * 64 + lane] * __int_as_float(e3.y);
    }
    for (; e < end; ++e) {
        int2 t = ep[e];
        acc0 += ht[(long)t.x * 64 + lane] * __int_as_float(t.y);
    }
    float v = ((acc0 + acc1) + (acc2 + acc3)) * indeg_inv[wave] + bias[lane];
    out[(long)wave * 64 + lane] = tanhf(v);
}

// C=32 + fused K=32->1 transform: one wave per node; halves process alternating edges;
// epilogue: h2 = tanh(agg*indeg+b1); ht2[n] = h2 . W2  (32-lane dot, shuffle reduce)
__global__ void agg32_dot_kernel(const float* __restrict__ ht, const int* __restrict__ row_off,
                                 const int2* __restrict__ ep,
                                 const float* __restrict__ indeg_inv, const float* __restrict__ bias,
                                 const float* __restrict__ W2, float* __restrict__ ht2, int N) {
    __shared__ float Ws2[32];
    if (threadIdx.x < 32) Ws2[threadIdx.x] = W2[threadIdx.x];
    __syncthreads();
    int wave = (blockIdx.x * blockDim.x + threadIdx.x) >> 6;
    int lane = threadIdx.x & 63;
    int c = lane & 31, half = lane >> 5;
    if (wave >= N) return;
    int beg = row_off[wave], end = row_off[wave + 1];
    float acc0 = 0.0f, acc1 = 0.0f;
    int e = beg + half;
    for (; e + 2 < end; e += 4) {
        int2 t0 = ep[e], t1 = ep[e + 2];
        acc0 += ht[(long)t0.x * 32 + c] * __int_as_float(t0.y);
        acc1 += ht[(long)t1.x * 32 + c] * __int_as_float(t1.y);
    }
    if (e < end) {
        int2 t = ep[e];
        acc0 += ht[(long)t.x * 32 + c] * __int_as_float(t.y);
    }
    float acc = acc0 + acc1;
    acc += __shfl_xor(acc, 32, 64);          // combine halves; both halves now hold full sum
    float v = tanhf(acc * indeg_inv[wave] + bias[c]);
    float t = v * Ws2[c];
    #pragma unroll
    for (int s = 16; s >= 1; s >>= 1) t += __shfl_xor(t, s, 64);  // reduce within 32-lane half
    if (lane == 0) ht2[wave] = t;
}

// C=1 final aggregation: one thread per node (ht2 table is 400 KB -> L2-resident gather)
__global__ void agg1_kernel(const float* __restrict__ ht2, const int* __restrict__ row_off,
                            const int2* __restrict__ ep,
                            const float* __restrict__ indeg_inv, const float* __restrict__ bias,
                            float* __restrict__ out, int N) {
    int n = blockIdx.x * blockDim.x + threadIdx.x;
    if (n >= N) return;
    int beg = row_off[n], end = row_off[n + 1];
    float acc = 0.0f;
    for (int e = beg; e < end; ++e) {
        int2 t = ep[e];
        acc += ht2[t.x] * __int_as_float(t.y);
    }
    out[n] = acc * indeg_inv[n] + bias[0];
}

extern "C" void kernel_launch(void* const* d_in, const int* in_sizes, int n_in,
                              void* d_out, int out_size, void* d_ws, size_t ws_size,
                              hipStream_t stream) {
    const float* b_z = (const float*)d_in[0];
    const int*   src = (const int*)d_in[1];
    const int*   dst = (const int*)d_in[2];
    const float* ew  = (const float*)d_in[3];
    const float* W0 = (const float*)d_in[5];
    const float* b0 = (const float*)d_in[6];
    const float* W1 = (const float*)d_in[7];
    const float* b1 = (const float*)d_in[8];
    const float* W2 = (const float*)d_in[9];
    const float* b2 = (const float*)d_in[10];
    float* out = (float*)d_out;

    const int N = N_NODES;
    const int E = N_EDGES;

    // workspace layout (all segments 16B-aligned)
    char* p = (char*)d_ws;
    int*   cnt_out    = (int*)p;            p += (size_t)N * 4;        // zeroed
    int*   cnt_in     = (int*)p;            p += (size_t)N * 4;        // zeroed (contiguous w/ cnt_out)
    int*   row_off    = (int*)p;            p += (size_t)(N + 4) * 4;  // keep 16B align after
    float* outdeg_inv = (float*)p;          p += (size_t)N * 4;
    float* indeg_inv  = (float*)p;          p += (size_t)N * 4;
    int2*  edge_perm  = (int2*)p;           p += (size_t)E * 8;
    float* bufA       = (float*)p;          p += (size_t)N * 64 * 4;
    float* bufB       = (float*)p;
    // aliases (lifetimes don't overlap):
    int*   rank = (int*)bufA;   // used between deg_rank and fill, before gemm0 writes bufA
    float* ht2  = (float*)bufB; // used after bufB's h1 is consumed by gemm1

    // ---- degree counts + ranks ----
    hipMemsetAsync(cnt_out, 0, 2L * N * sizeof(int), stream);
    deg_rank_kernel<<<(E + 255) / 256, 256, 0, stream>>>(src, dst, cnt_out, cnt_in, rank, E);

    // ---- scan + deg^-1/2 (single block) ----
    scan_fused_kernel<<<1, 1024, 0, stream>>>((const int4*)cnt_in, (const int4*)cnt_out,
                                              row_off, outdeg_inv, indeg_inv, N / 4, E);

    // ---- CSR fill (atomic-free) ----
    fill_csr_kernel<<<(E + 255) / 256, 256, 0, stream>>>(src, dst, ew, rank, row_off,
                                                         outdeg_inv, edge_perm, E);

    // ---- layer 0: 128 -> 64, tanh ----
    gemm_tile_kernel<128, 64, 4><<<N / 64, 256, 0, stream>>>(b_z, W0, bufA);
    agg64_kernel<<<N / 4, 256, 0, stream>>>(bufA, row_off, edge_perm, indeg_inv, b0, bufB, N);

    // ---- layer 1: 64 -> 32, tanh; layer-2 transform fused into agg ----
    gemm_tile_kernel<64, 32, 2><<<N / 64, 256, 0, stream>>>(bufB, W1, bufA);
    agg32_dot_kernel<<<N / 4, 256, 0, stream>>>(bufA, row_off, edge_perm, indeg_inv, b1, W2, ht2, N);

    // ---- layer 2 aggregation -> out ----
    agg1_kernel<<<(N + 255) / 256, 256, 0, stream>>>(ht2, row_off, edge_perm, indeg_inv, b2, out, N);
}

// Round 6
// 420.195 us; speedup vs baseline: 2.7145x; 1.3407x over previous
//
#include <hip/hip_runtime.h>
#include <math.h>

#define N_NODES 102400
#define N_EDGES 1638400
#define NB 100            // coarse buckets: node range 1024 (102400/1024)
#define PB 256            // partition blocks
#define EPB (N_EDGES/PB)  // 6400 edges per partition block

// ---- pass A: per-block coarse histograms of dst>>10 and src>>10 (LDS, atomic-free globally) ----
__global__ __launch_bounds__(256) void histA_kernel(const int* __restrict__ src, const int* __restrict__ dst,
                                                    int* __restrict__ histD, int* __restrict__ histS) {
    __shared__ int hD[NB], hS[NB];
    int tid = threadIdx.x;
    if (tid < NB) { hD[tid] = 0; hS[tid] = 0; }
    __syncthreads();
    int base = blockIdx.x * EPB;
    for (int i = tid; i < EPB; i += 256) {
        atomicAdd(&hD[dst[base + i] >> 10], 1);   // LDS atomic (CU-local)
        atomicAdd(&hS[src[base + i] >> 10], 1);
    }
    __syncthreads();
    if (tid < NB) {
        histD[blockIdx.x * NB + tid] = hD[tid];
        histS[blockIdx.x * NB + tid] = hS[tid];
    }
}

// ---- pass B: scan block-bucket matrices -> per-(block,bucket) offsets + coarse bases ----
__global__ __launch_bounds__(256) void scanB_kernel(const int* __restrict__ histD, const int* __restrict__ histS,
                                                    int* __restrict__ offD, int* __restrict__ offS,
                                                    int* __restrict__ coarseD, int* __restrict__ coarseS) {
    __shared__ int totD[NB], totS[NB], baseD[NB + 1], baseS[NB + 1];
    int t = threadIdx.x;
    if (t < NB) { int s = 0; for (int k = 0; k < PB; k++) s += histD[k * NB + t]; totD[t] = s; }
    else if (t >= 128 && t < 128 + NB) { int j = t - 128; int s = 0; for (int k = 0; k < PB; k++) s += histS[k * NB + j]; totS[j] = s; }
    __syncthreads();
    if (t == 0)   { int r = 0; for (int j = 0; j < NB; j++) { baseD[j] = r; r += totD[j]; } baseD[NB] = r; }
    if (t == 128) { int r = 0; for (int j = 0; j < NB; j++) { baseS[j] = r; r += totS[j]; } baseS[NB] = r; }
    __syncthreads();
    if (t < NB) { int r = baseD[t]; for (int k = 0; k < PB; k++) { offD[k * NB + t] = r; r += histD[k * NB + t]; } }
    else if (t >= 128 && t < 128 + NB) { int j = t - 128; int r = baseS[j]; for (int k = 0; k < PB; k++) { offS[k * NB + j] = r; r += histS[k * NB + j]; } }
    if (t <= NB) coarseD[t] = baseD[t];
    if (t >= 128 && t <= 128 + NB) coarseS[t - 128] = baseS[t - 128];
}

// ---- pass C: partition edges into coarse buckets (LDS cursors, disjoint global slices) ----
__global__ __launch_bounds__(256) void partC_kernel(const int* __restrict__ src, const int* __restrict__ dst,
                                                    const float* __restrict__ ew,
                                                    const int* __restrict__ offD, const int* __restrict__ offS,
                                                    int2* __restrict__ partD, int* __restrict__ partS) {
    __shared__ int cD[NB], cS[NB];
    int tid = threadIdx.x;
    if (tid < NB) { cD[tid] = offD[blockIdx.x * NB + tid]; cS[tid] = offS[blockIdx.x * NB + tid]; }
    __syncthreads();
    int base = blockIdx.x * EPB;
    for (int i = tid; i < EPB; i += 256) {
        int s = src[base + i], d = dst[base + i];
        float w = ew[base + i];
        int p = atomicAdd(&cD[d >> 10], 1);              // LDS atomic
        partD[p] = make_int2(s | ((d & 1023) << 17), __float_as_int(w));
        int q = atomicAdd(&cS[s >> 10], 1);              // LDS atomic
        partS[q] = s & 1023;
    }
}

// ---- pass D2: per src-bucket fine histogram -> outdeg_inv ----
__global__ __launch_bounds__(1024) void fineS_kernel(const int* __restrict__ partS, const int* __restrict__ coarseS,
                                                     float* __restrict__ outdeg_inv) {
    __shared__ int hist[1024];
    int tid = threadIdx.x;
    hist[tid] = 0;
    __syncthreads();
    int beg = coarseS[blockIdx.x], end = coarseS[blockIdx.x + 1];
    for (int i = beg + tid; i < end; i += 1024) atomicAdd(&hist[partS[i]], 1);
    __syncthreads();
    outdeg_inv[blockIdx.x * 1024 + tid] = 1.0f / sqrtf((float)max(hist[tid], 1));
}

// ---- pass D: per dst-bucket fine sort -> row_off, indeg_inv, final CSR (weights pre-scaled) ----
__global__ __launch_bounds__(1024) void fineD_kernel(const int2* __restrict__ partD, const int* __restrict__ coarseD,
                                                     const float* __restrict__ outdeg_inv,
                                                     int2* __restrict__ edge_perm, int* __restrict__ row_off,
                                                     float* __restrict__ indeg_inv) {
    __shared__ int hist[1024], cursor[1024];
    __shared__ int wsum[16];
    int tid = threadIdx.x, lane = tid & 63, wid = tid >> 6;
    hist[tid] = 0;
    __syncthreads();
    int beg = coarseD[blockIdx.x], end = coarseD[blockIdx.x + 1];
    for (int i = beg + tid; i < end; i += 1024) atomicAdd(&hist[(partD[i].x >> 17) & 1023], 1);
    __syncthreads();
    // exclusive scan of hist across the block
    int v = hist[tid];
    int x = v;
    #pragma unroll
    for (int s = 1; s < 64; s <<= 1) { int t = __shfl_up(x, s, 64); if (lane >= s) x += t; }
    if (lane == 63) wsum[wid] = x;
    __syncthreads();
    if (wid == 0) {
        int ws = (lane < 16) ? wsum[lane] : 0;
        int y = ws;
        #pragma unroll
        for (int s = 1; s < 16; s <<= 1) { int t = __shfl_up(y, s, 64); if (lane >= s) y += t; }
        if (lane < 16) wsum[lane] = y - ws;
    }
    __syncthreads();
    int ex = wsum[wid] + x - v;                 // exclusive scan value for this node
    cursor[tid] = beg + ex;
    int node = blockIdx.x * 1024 + tid;
    row_off[node] = beg + ex;
    indeg_inv[node] = 1.0f / sqrtf((float)max(v, 1));
    if (blockIdx.x == NB - 1 && tid == 0) row_off[N_NODES] = N_EDGES;
    __syncthreads();
    for (int i = beg + tid; i < end; i += 1024) {
        int2 t2 = partD[i];
        int d = (t2.x >> 17) & 1023, s = t2.x & 0x1FFFF;
        int p = atomicAdd(&cursor[d], 1);       // LDS atomic
        float w = __int_as_float(t2.y) * outdeg_inv[s];
        edge_perm[p] = make_int2(s, __float_as_int(w));
    }
}

// ---------------- register-tiled node transform: out = h @ W ----------------
template<int K, int C, int RN>
__global__ __launch_bounds__(256) void gemm_tile_kernel(
    const float* __restrict__ h, const float* __restrict__ W, float* __restrict__ out) {
    constexpr int BM = 64;
    constexpr int RM = 4;
    constexpr int KC = 64;
    constexpr int TX = C / RN;               // 16
    constexpr int TY = BM / RM;              // 16
    static_assert(TX * TY == 256, "bad tile");

    __shared__ float Ws[K * C];
    __shared__ float Hs[KC][BM + 4];

    const int tid = threadIdx.x;
    const long brow = (long)blockIdx.x * BM;

    for (int i = tid; i < K * C; i += 256) Ws[i] = W[i];

    const int tx = tid % TX;
    const int ty = tid / TX;
    float acc[RM][RN] = {};

    const int lr = tid % 16;
    const int lk = tid / 16;

    for (int kc = 0; kc < K; kc += KC) {
        __syncthreads();
        #pragma unroll
        for (int p0 = 0; p0 < BM; p0 += 16) {
            const int r = p0 + lr;
            const float4 hv = *(const float4*)(h + (brow + r) * K + kc + lk * 4);
            Hs[lk * 4 + 0][r] = hv.x;
            Hs[lk * 4 + 1][r] = hv.y;
            Hs[lk * 4 + 2][r] = hv.z;
            Hs[lk * 4 + 3][r] = hv.w;
        }
        __syncthreads();

        #pragma unroll
        for (int k = 0; k < KC; ++k) {
            const float4 a4 = *(const float4*)&Hs[k][ty * RM];
            const float av[RM] = {a4.x, a4.y, a4.z, a4.w};
            float b[RN];
            if constexpr (RN == 4) {
                *(float4*)b = *(const float4*)&Ws[(kc + k) * C + tx * RN];
            } else {
                *(float2*)b = *(const float2*)&Ws[(kc + k) * C + tx * RN];
            }
            #pragma unroll
            for (int i = 0; i < RM; ++i)
                #pragma unroll
                for (int j = 0; j < RN; ++j)
                    acc[i][j] += av[i] * b[j];
        }
    }

    #pragma unroll
    for (int i = 0; i < RM; ++i) {
        const long row = brow + ty * RM + i;
        if constexpr (RN == 4) {
            float4 v = {acc[i][0], acc[i][1], acc[i][2], acc[i][3]};
            *(float4*)(out + row * C + tx * RN) = v;
        } else {
            float2 v = {acc[i][0], acc[i][1]};
            *(float2*)(out + row * C + tx * RN) = v;
        }
    }
}

// ---------------- CSR aggregation, fused finalize ----------------
__global__ void agg64_kernel(const float* __restrict__ ht, const int* __restrict__ row_off,
                             const int2* __restrict__ ep,
                             const float* __restrict__ indeg_inv, const float* __restrict__ bias,
                             float* __restrict__ out, int N) {
    int wave = (blockIdx.x * blockDim.x + threadIdx.x) >> 6;
    int lane = threadIdx.x & 63;
    if (wave >= N) return;
    int beg = row_off[wave], end = row_off[wave + 1];
    float acc0 = 0.0f, acc1 = 0.0f, acc2 = 0.0f, acc3 = 0.0f;
    int e = beg;
    for (; e + 3 < end; e += 4) {
        int2 e0 = ep[e], e1 = ep[e + 1], e2 = ep[e + 2], e3 = ep[e + 3];
        acc0 += ht[(long)e0.x * 64 + lane] * __int_as_float(e0.y);
        acc1 += ht[(long)e1.x * 64 + lane] * __int_as_float(e1.y);
        acc2 += ht[(long)e2.x * 64 + lane] * __int_as_float(e2.y);
        acc3 += ht[(long)e3.x * 64 + lane] * __int_as_float(e3.y);
    }
    for (; e < end; ++e) {
        int2 t = ep[e];
        acc0 += ht[(long)t.x * 64 + lane] * __int_as_float(t.y);
    }
    float v = ((acc0 + acc1) + (acc2 + acc3)) * indeg_inv[wave] + bias[lane];
    out[(long)wave * 64 + lane] = tanhf(v);
}

// C=32 agg + fused K=32->1 transform
__global__ void agg32_dot_kernel(const float* __restrict__ ht, const int* __restrict__ row_off,
                                 const int2* __restrict__ ep,
                                 const float* __restrict__ indeg_inv, const float* __restrict__ bias,
                                 const float* __restrict__ W2, float* __restrict__ ht2, int N) {
    __shared__ float Ws2[32];
    if (threadIdx.x < 32) Ws2[threadIdx.x] = W2[threadIdx.x];
    __syncthreads();
    int wave = (blockIdx.x * blockDim.x + threadIdx.x) >> 6;
    int lane = threadIdx.x & 63;
    int c = lane & 31, half = lane >> 5;
    if (wave >= N) return;
    int beg = row_off[wave], end = row_off[wave + 1];
    float acc0 = 0.0f, acc1 = 0.0f;
    int e = beg + half;
    for (; e + 2 < end; e += 4) {
        int2 t0 = ep[e], t1 = ep[e + 2];
        acc0 += ht[(long)t0.x * 32 + c] * __int_as_float(t0.y);
        acc1 += ht[(long)t1.x * 32 + c] * __int_as_float(t1.y);
    }
    if (e < end) {
        int2 t = ep[e];
        acc0 += ht[(long)t.x * 32 + c] * __int_as_float(t.y);
    }
    float acc = acc0 + acc1;
    acc += __shfl_xor(acc, 32, 64);
    float v = tanhf(acc * indeg_inv[wave] + bias[c]);
    float t = v * Ws2[c];
    #pragma unroll
    for (int s = 16; s >= 1; s >>= 1) t += __shfl_xor(t, s, 64);
    if (lane == 0) ht2[wave] = t;
}

// C=1 final aggregation
__global__ void agg1_kernel(const float* __restrict__ ht2, const int* __restrict__ row_off,
                            const int2* __restrict__ ep,
                            const float* __restrict__ indeg_inv, const float* __restrict__ bias,
                            float* __restrict__ out, int N) {
    int n = blockIdx.x * blockDim.x + threadIdx.x;
    if (n >= N) return;
    int beg = row_off[n], end = row_off[n + 1];
    float acc = 0.0f;
    for (int e = beg; e < end; ++e) {
        int2 t = ep[e];
        acc += ht2[t.x] * __int_as_float(t.y);
    }
    out[n] = acc * indeg_inv[n] + bias[0];
}

extern "C" void kernel_launch(void* const* d_in, const int* in_sizes, int n_in,
                              void* d_out, int out_size, void* d_ws, size_t ws_size,
                              hipStream_t stream) {
    const float* b_z = (const float*)d_in[0];
    const int*   src = (const int*)d_in[1];
    const int*   dst = (const int*)d_in[2];
    const float* ew  = (const float*)d_in[3];
    const float* W0 = (const float*)d_in[5];
    const float* b0 = (const float*)d_in[6];
    const float* W1 = (const float*)d_in[7];
    const float* b1 = (const float*)d_in[8];
    const float* W2 = (const float*)d_in[9];
    const float* b2 = (const float*)d_in[10];
    float* out = (float*)d_out;

    const int N = N_NODES;
    const int E = N_EDGES;

    // workspace layout (16B-aligned segments)
    char* p = (char*)d_ws;
    int*   row_off    = (int*)p;            p += (size_t)(N + 4) * 4;
    float* outdeg_inv = (float*)p;          p += (size_t)N * 4;
    float* indeg_inv  = (float*)p;          p += (size_t)N * 4;
    int*   histD      = (int*)p;            p += (size_t)PB * NB * 4;
    int*   histS      = (int*)p;            p += (size_t)PB * NB * 4;
    int*   offD       = (int*)p;            p += (size_t)PB * NB * 4;
    int*   offS       = (int*)p;            p += (size_t)PB * NB * 4;
    int*   coarseD    = (int*)p;            p += (size_t)(NB + 4) * 4;
    int*   coarseS    = (int*)p;            p += (size_t)(NB + 4) * 4;
    int2*  edge_perm  = (int2*)p;           p += (size_t)E * 8;
    float* bufA       = (float*)p;          p += (size_t)N * 64 * 4;
    float* bufB       = (float*)p;
    // aliases with disjoint lifetimes (partD/partS dead before gemm0/agg64 write bufA/bufB):
    int2* partD = (int2*)bufA;   // E * 8 B = 13 MB  <= 26 MB
    int*  partS = (int*)bufB;    // E * 4 B = 6.5 MB <= 26 MB
    float* ht2  = (float*)bufB;  // reused after bufB's h1 consumed by gemm1 (agg32 writes ht2)

    // ---- atomic-free CSR build (two-level counting sort) ----
    histA_kernel<<<PB, 256, 0, stream>>>(src, dst, histD, histS);
    scanB_kernel<<<1, 256, 0, stream>>>(histD, histS, offD, offS, coarseD, coarseS);
    partC_kernel<<<PB, 256, 0, stream>>>(src, dst, ew, offD, offS, partD, partS);
    fineS_kernel<<<NB, 1024, 0, stream>>>(partS, coarseS, outdeg_inv);
    fineD_kernel<<<NB, 1024, 0, stream>>>(partD, coarseD, outdeg_inv, edge_perm, row_off, indeg_inv);

    // ---- layer 0: 128 -> 64, tanh ----
    gemm_tile_kernel<128, 64, 4><<<N / 64, 256, 0, stream>>>(b_z, W0, bufA);
    agg64_kernel<<<N / 4, 256, 0, stream>>>(bufA, row_off, edge_perm, indeg_inv, b0, bufB, N);

    // ---- layer 1: 64 -> 32, tanh; layer-2 transform fused into agg ----
    gemm_tile_kernel<64, 32, 2><<<N / 64, 256, 0, stream>>>(bufB, W1, bufA);
    agg32_dot_kernel<<<N / 4, 256, 0, stream>>>(bufA, row_off, edge_perm, indeg_inv, b1, W2, ht2, N);

    // ---- layer 2 aggregation -> out ----
    agg1_kernel<<<(N + 255) / 256, 256, 0, stream>>>(ht2, row_off, edge_perm, indeg_inv, b2, out, N);
}

// Round 7
// 394.604 us; speedup vs baseline: 2.8905x; 1.0649x over previous
//
#include <hip/hip_runtime.h>
#include <math.h>

#define N_NODES 102400
#define N_EDGES 1638400
#define NB 100            // coarse buckets: node range 1024 (102400/1024)
#define PB 256            // partition blocks
#define EPB (N_EDGES/PB)  // 6400 edges per partition block

// ---- pass A: per-block coarse histograms of dst>>10 and src>>10 (LDS, atomic-free globally) ----
__global__ __launch_bounds__(256) void histA_kernel(const int* __restrict__ src, const int* __restrict__ dst,
                                                    int* __restrict__ histD, int* __restrict__ histS) {
    __shared__ int hD[NB], hS[NB];
    int tid = threadIdx.x;
    if (tid < NB) { hD[tid] = 0; hS[tid] = 0; }
    __syncthreads();
    int base = blockIdx.x * EPB;
    for (int i = tid; i < EPB; i += 256) {
        atomicAdd(&hD[dst[base + i] >> 10], 1);   // LDS atomic (CU-local)
        atomicAdd(&hS[src[base + i] >> 10], 1);
    }
    __syncthreads();
    if (tid < NB) {
        histD[blockIdx.x * NB + tid] = hD[tid];
        histS[blockIdx.x * NB + tid] = hS[tid];
    }
}

// ---- pass B: scan block-bucket matrices -> per-(block,bucket) offsets + coarse bases ----
__global__ __launch_bounds__(256) void scanB_kernel(const int* __restrict__ histD, const int* __restrict__ histS,
                                                    int* __restrict__ offD, int* __restrict__ offS,
                                                    int* __restrict__ coarseD, int* __restrict__ coarseS) {
    __shared__ int totD[NB], totS[NB], baseD[NB + 1], baseS[NB + 1];
    int t = threadIdx.x;
    if (t < NB) { int s = 0; for (int k = 0; k < PB; k++) s += histD[k * NB + t]; totD[t] = s; }
    else if (t >= 128 && t < 128 + NB) { int j = t - 128; int s = 0; for (int k = 0; k < PB; k++) s += histS[k * NB + j]; totS[j] = s; }
    __syncthreads();
    if (t == 0)   { int r = 0; for (int j = 0; j < NB; j++) { baseD[j] = r; r += totD[j]; } baseD[NB] = r; }
    if (t == 128) { int r = 0; for (int j = 0; j < NB; j++) { baseS[j] = r; r += totS[j]; } baseS[NB] = r; }
    __syncthreads();
    if (t < NB) { int r = baseD[t]; for (int k = 0; k < PB; k++) { offD[k * NB + t] = r; r += histD[k * NB + t]; } }
    else if (t >= 128 && t < 128 + NB) { int j = t - 128; int r = baseS[j]; for (int k = 0; k < PB; k++) { offS[k * NB + j] = r; r += histS[k * NB + j]; } }
    if (t <= NB) coarseD[t] = baseD[t];
    if (t >= 128 && t <= 128 + NB) coarseS[t - 128] = baseS[t - 128];
}

// ---- pass C: partition edges into coarse buckets (LDS cursors, disjoint global slices) ----
__global__ __launch_bounds__(256) void partC_kernel(const int* __restrict__ src, const int* __restrict__ dst,
                                                    const float* __restrict__ ew,
                                                    const int* __restrict__ offD, const int* __restrict__ offS,
                                                    int2* __restrict__ partD, int* __restrict__ partS) {
    __shared__ int cD[NB], cS[NB];
    int tid = threadIdx.x;
    if (tid < NB) { cD[tid] = offD[blockIdx.x * NB + tid]; cS[tid] = offS[blockIdx.x * NB + tid]; }
    __syncthreads();
    int base = blockIdx.x * EPB;
    for (int i = tid; i < EPB; i += 256) {
        int s = src[base + i], d = dst[base + i];
        float w = ew[base + i];
        int p = atomicAdd(&cD[d >> 10], 1);              // LDS atomic
        partD[p] = make_int2(s | ((d & 1023) << 17), __float_as_int(w));
        int q = atomicAdd(&cS[s >> 10], 1);              // LDS atomic
        partS[q] = s & 1023;
    }
}

// ---- pass D2: per src-bucket fine histogram -> outdeg_inv ----
__global__ __launch_bounds__(1024) void fineS_kernel(const int* __restrict__ partS, const int* __restrict__ coarseS,
                                                     float* __restrict__ outdeg_inv) {
    __shared__ int hist[1024];
    int tid = threadIdx.x;
    hist[tid] = 0;
    __syncthreads();
    int beg = coarseS[blockIdx.x], end = coarseS[blockIdx.x + 1];
    for (int i = beg + tid; i < end; i += 1024) atomicAdd(&hist[partS[i]], 1);
    __syncthreads();
    outdeg_inv[blockIdx.x * 1024 + tid] = 1.0f / sqrtf((float)max(hist[tid], 1));
}

// ---- pass D: per dst-bucket fine sort -> row_off, indeg_inv, final CSR (weights pre-scaled) ----
__global__ __launch_bounds__(1024) void fineD_kernel(const int2* __restrict__ partD, const int* __restrict__ coarseD,
                                                     const float* __restrict__ outdeg_inv,
                                                     int2* __restrict__ edge_perm, int* __restrict__ row_off,
                                                     float* __restrict__ indeg_inv) {
    __shared__ int hist[1024], cursor[1024];
    __shared__ int wsum[16];
    int tid = threadIdx.x, lane = tid & 63, wid = tid >> 6;
    hist[tid] = 0;
    __syncthreads();
    int beg = coarseD[blockIdx.x], end = coarseD[blockIdx.x + 1];
    for (int i = beg + tid; i < end; i += 1024) atomicAdd(&hist[(partD[i].x >> 17) & 1023], 1);
    __syncthreads();
    // exclusive scan of hist across the block
    int v = hist[tid];
    int x = v;
    #pragma unroll
    for (int s = 1; s < 64; s <<= 1) { int t = __shfl_up(x, s, 64); if (lane >= s) x += t; }
    if (lane == 63) wsum[wid] = x;
    __syncthreads();
    if (wid == 0) {
        int ws = (lane < 16) ? wsum[lane] : 0;
        int y = ws;
        #pragma unroll
        for (int s = 1; s < 16; s <<= 1) { int t = __shfl_up(y, s, 64); if (lane >= s) y += t; }
        if (lane < 16) wsum[lane] = y - ws;
    }
    __syncthreads();
    int ex = wsum[wid] + x - v;                 // exclusive scan value for this node
    cursor[tid] = beg + ex;
    int node = blockIdx.x * 1024 + tid;
    row_off[node] = beg + ex;
    indeg_inv[node] = 1.0f / sqrtf((float)max(v, 1));
    if (blockIdx.x == NB - 1 && tid == 0) row_off[N_NODES] = N_EDGES;
    __syncthreads();
    for (int i = beg + tid; i < end; i += 1024) {
        int2 t2 = partD[i];
        int d = (t2.x >> 17) & 1023, s = t2.x & 0x1FFFF;
        int p = atomicAdd(&cursor[d], 1);       // LDS atomic
        float w = __int_as_float(t2.y) * outdeg_inv[s];
        edge_perm[p] = make_int2(s, __float_as_int(w));
    }
}

// ---------------- register-tiled node transform: out = h @ W ----------------
template<int K, int C, int RN>
__global__ __launch_bounds__(256) void gemm_tile_kernel(
    const float* __restrict__ h, const float* __restrict__ W, float* __restrict__ out) {
    constexpr int BM = 64;
    constexpr int RM = 4;
    constexpr int KC = 64;
    constexpr int TX = C / RN;               // 16
    constexpr int TY = BM / RM;              // 16
    static_assert(TX * TY == 256, "bad tile");

    __shared__ float Ws[K * C];
    __shared__ float Hs[KC][BM + 4];

    const int tid = threadIdx.x;
    const long brow = (long)blockIdx.x * BM;

    for (int i = tid; i < K * C; i += 256) Ws[i] = W[i];

    const int tx = tid % TX;
    const int ty = tid / TX;
    float acc[RM][RN] = {};

    const int lr = tid % 16;
    const int lk = tid / 16;

    for (int kc = 0; kc < K; kc += KC) {
        __syncthreads();
        #pragma unroll
        for (int p0 = 0; p0 < BM; p0 += 16) {
            const int r = p0 + lr;
            const float4 hv = *(const float4*)(h + (brow + r) * K + kc + lk * 4);
            Hs[lk * 4 + 0][r] = hv.x;
            Hs[lk * 4 + 1][r] = hv.y;
            Hs[lk * 4 + 2][r] = hv.z;
            Hs[lk * 4 + 3][r] = hv.w;
        }
        __syncthreads();

        #pragma unroll
        for (int k = 0; k < KC; ++k) {
            const float4 a4 = *(const float4*)&Hs[k][ty * RM];
            const float av[RM] = {a4.x, a4.y, a4.z, a4.w};
            float b[RN];
            if constexpr (RN == 4) {
                *(float4*)b = *(const float4*)&Ws[(kc + k) * C + tx * RN];
            } else {
                *(float2*)b = *(const float2*)&Ws[(kc + k) * C + tx * RN];
            }
            #pragma unroll
            for (int i = 0; i < RM; ++i)
                #pragma unroll
                for (int j = 0; j < RN; ++j)
                    acc[i][j] += av[i] * b[j];
        }
    }

    #pragma unroll
    for (int i = 0; i < RM; ++i) {
        const long row = brow + ty * RM + i;
        if constexpr (RN == 4) {
            float4 v = {acc[i][0], acc[i][1], acc[i][2], acc[i][3]};
            *(float4*)(out + row * C + tx * RN) = v;
        } else {
            float2 v = {acc[i][0], acc[i][1]};
            *(float2*)(out + row * C + tx * RN) = v;
        }
    }
}

// ---------------- CSR aggregation, fused finalize ----------------
// C=64: one wave per node. lane = eslot(0..3) x chunk(0..15); each lane loads float4 of
// its edge's src row -> ONE global_load_dwordx4 per 4 edges per wave (4 rows x 256B = 1KB).
__global__ void agg64_kernel(const float* __restrict__ ht, const int* __restrict__ row_off,
                             const int2* __restrict__ ep,
                             const float* __restrict__ indeg_inv, const float* __restrict__ bias,
                             float* __restrict__ out, int N) {
    int wave = (blockIdx.x * blockDim.x + threadIdx.x) >> 6;
    int lane = threadIdx.x & 63;
    if (wave >= N) return;
    int chunk = lane & 15;       // channels 4*chunk .. 4*chunk+3
    int eslot = lane >> 4;       // 0..3
    int beg = row_off[wave], end = row_off[wave + 1];
    float4 acc = {0.0f, 0.0f, 0.0f, 0.0f};
    for (int e = beg; e < end; e += 4) {
        int ei = e + eslot;
        int2 ed = ep[min(ei, end - 1)];
        float w = (ei < end) ? __int_as_float(ed.y) : 0.0f;
        float4 hv = *(const float4*)(ht + (long)ed.x * 64 + chunk * 4);
        acc.x += hv.x * w; acc.y += hv.y * w; acc.z += hv.z * w; acc.w += hv.w * w;
    }
    // butterfly-reduce across eslot (lane bits 4,5); all lanes end with chunk sums
    #pragma unroll
    for (int s = 16; s <= 32; s <<= 1) {
        acc.x += __shfl_xor(acc.x, s, 64);
        acc.y += __shfl_xor(acc.y, s, 64);
        acc.z += __shfl_xor(acc.z, s, 64);
        acc.w += __shfl_xor(acc.w, s, 64);
    }
    if (eslot == 0) {
        float sc = indeg_inv[wave];
        float4 b = *(const float4*)(bias + chunk * 4);
        float4 v;
        v.x = tanhf(acc.x * sc + b.x);
        v.y = tanhf(acc.y * sc + b.y);
        v.z = tanhf(acc.z * sc + b.z);
        v.w = tanhf(acc.w * sc + b.w);
        *(float4*)(out + (long)wave * 64 + chunk * 4) = v;
    }
}

// C=32 agg + fused K=32->1 transform: lane = eslot(0..7) x chunk(0..7);
// one dwordx4 per 8 edges per wave (8 rows x 128B = 1KB).
__global__ void agg32_dot_kernel(const float* __restrict__ ht, const int* __restrict__ row_off,
                                 const int2* __restrict__ ep,
                                 const float* __restrict__ indeg_inv, const float* __restrict__ bias,
                                 const float* __restrict__ W2, float* __restrict__ ht2, int N) {
    int wave = (blockIdx.x * blockDim.x + threadIdx.x) >> 6;
    int lane = threadIdx.x & 63;
    if (wave >= N) return;
    int chunk = lane & 7;        // channels 4*chunk .. 4*chunk+3
    int eslot = lane >> 3;       // 0..7
    int beg = row_off[wave], end = row_off[wave + 1];
    float4 acc = {0.0f, 0.0f, 0.0f, 0.0f};
    for (int e = beg; e < end; e += 8) {
        int ei = e + eslot;
        int2 ed = ep[min(ei, end - 1)];
        float w = (ei < end) ? __int_as_float(ed.y) : 0.0f;
        float4 hv = *(const float4*)(ht + (long)ed.x * 32 + chunk * 4);
        acc.x += hv.x * w; acc.y += hv.y * w; acc.z += hv.z * w; acc.w += hv.w * w;
    }
    // butterfly-reduce across eslot (lane bits 3,4,5)
    #pragma unroll
    for (int s = 8; s <= 32; s <<= 1) {
        acc.x += __shfl_xor(acc.x, s, 64);
        acc.y += __shfl_xor(acc.y, s, 64);
        acc.z += __shfl_xor(acc.z, s, 64);
        acc.w += __shfl_xor(acc.w, s, 64);
    }
    float sc = indeg_inv[wave];
    float4 b = *(const float4*)(bias + chunk * 4);
    float4 w2 = *(const float4*)(W2 + chunk * 4);
    float t = tanhf(acc.x * sc + b.x) * w2.x
            + tanhf(acc.y * sc + b.y) * w2.y
            + tanhf(acc.z * sc + b.z) * w2.z
            + tanhf(acc.w * sc + b.w) * w2.w;
    t += __shfl_xor(t, 1, 64);
    t += __shfl_xor(t, 2, 64);
    t += __shfl_xor(t, 4, 64);
    if (lane == 0) ht2[wave] = t;
}

// C=1 final aggregation: 16 lanes per node (4 nodes/wave); coalesced edge reads
__global__ void agg1_kernel(const float* __restrict__ ht2, const int* __restrict__ row_off,
                            const int2* __restrict__ ep,
                            const float* __restrict__ indeg_inv, const float* __restrict__ bias,
                            float* __restrict__ out, int N) {
    int wave = (blockIdx.x * blockDim.x + threadIdx.x) >> 6;
    int lane = threadIdx.x & 63;
    int sub = lane >> 4;         // 0..3
    int slot = lane & 15;
    int node = wave * 4 + sub;
    if (node >= N) return;
    int beg = row_off[node], end = row_off[node + 1];
    float acc = 0.0f;
    for (int e = beg + slot; e < end; e += 16) {
        int2 t = ep[e];
        acc += ht2[t.x] * __int_as_float(t.y);
    }
    #pragma unroll
    for (int s = 1; s <= 8; s <<= 1) acc += __shfl_xor(acc, s, 64);  // within 16-lane group
    if (slot == 0) out[node] = acc * indeg_inv[node] + bias[0];
}

extern "C" void kernel_launch(void* const* d_in, const int* in_sizes, int n_in,
                              void* d_out, int out_size, void* d_ws, size_t ws_size,
                              hipStream_t stream) {
    const float* b_z = (const float*)d_in[0];
    const int*   src = (const int*)d_in[1];
    const int*   dst = (const int*)d_in[2];
    const float* ew  = (const float*)d_in[3];
    const float* W0 = (const float*)d_in[5];
    const float* b0 = (const float*)d_in[6];
    const float* W1 = (const float*)d_in[7];
    const float* b1 = (const float*)d_in[8];
    const float* W2 = (const float*)d_in[9];
    const float* b2 = (const float*)d_in[10];
    float* out = (float*)d_out;

    const int N = N_NODES;
    const int E = N_EDGES;

    // workspace layout (16B-aligned segments)
    char* p = (char*)d_ws;
    int*   row_off    = (int*)p;            p += (size_t)(N + 4) * 4;
    float* outdeg_inv = (float*)p;          p += (size_t)N * 4;
    float* indeg_inv  = (float*)p;          p += (size_t)N * 4;
    int*   histD      = (int*)p;            p += (size_t)PB * NB * 4;
    int*   histS      = (int*)p;            p += (size_t)PB * NB * 4;
    int*   offD       = (int*)p;            p += (size_t)PB * NB * 4;
    int*   offS       = (int*)p;            p += (size_t)PB * NB * 4;
    int*   coarseD    = (int*)p;            p += (size_t)(NB + 4) * 4;
    int*   coarseS    = (int*)p;            p += (size_t)(NB + 4) * 4;
    int2*  edge_perm  = (int2*)p;           p += (size_t)E * 8;
    float* bufA       = (float*)p;          p += (size_t)N * 64 * 4;
    float* bufB       = (float*)p;
    // aliases with disjoint lifetimes (partD/partS dead before gemm0/agg64 write bufA/bufB):
    int2* partD = (int2*)bufA;   // E * 8 B = 13 MB  <= 26 MB
    int*  partS = (int*)bufB;    // E * 4 B = 6.5 MB <= 26 MB
    float* ht2  = (float*)bufB;  // reused after bufB's h1 consumed by gemm1 (agg32 writes ht2)

    // ---- atomic-free CSR build (two-level counting sort) ----
    histA_kernel<<<PB, 256, 0, stream>>>(src, dst, histD, histS);
    scanB_kernel<<<1, 256, 0, stream>>>(histD, histS, offD, offS, coarseD, coarseS);
    partC_kernel<<<PB, 256, 0, stream>>>(src, dst, ew, offD, offS, partD, partS);
    fineS_kernel<<<NB, 1024, 0, stream>>>(partS, coarseS, outdeg_inv);
    fineD_kernel<<<NB, 1024, 0, stream>>>(partD, coarseD, outdeg_inv, edge_perm, row_off, indeg_inv);

    // ---- layer 0: 128 -> 64, tanh ----
    gemm_tile_kernel<128, 64, 4><<<N / 64, 256, 0, stream>>>(b_z, W0, bufA);
    agg64_kernel<<<N / 4, 256, 0, stream>>>(bufA, row_off, edge_perm, indeg_inv, b0, bufB, N);

    // ---- layer 1: 64 -> 32, tanh; layer-2 transform fused into agg ----
    gemm_tile_kernel<64, 32, 2><<<N / 64, 256, 0, stream>>>(bufB, W1, bufA);
    agg32_dot_kernel<<<N / 4, 256, 0, stream>>>(bufA, row_off, edge_perm, indeg_inv, b1, W2, ht2, N);

    // ---- layer 2 aggregation -> out ----
    agg1_kernel<<<N / 16, 256, 0, stream>>>(ht2, row_off, edge_perm, indeg_inv, b2, out, N);
}

// Round 8
// 382.472 us; speedup vs baseline: 2.9822x; 1.0317x over previous
//
#include <hip/hip_runtime.h>
#include <math.h>

#define N_NODES 102400
#define N_EDGES 1638400
#define NB 100            // coarse buckets: node range 1024 (102400/1024)
#define PB 256            // partition blocks
#define EPB (N_EDGES/PB)  // 6400 edges per partition block

// ---- pass A: per-block coarse histograms of dst>>10 and src>>10 (LDS, atomic-free globally) ----
__global__ __launch_bounds__(256) void histA_kernel(const int* __restrict__ src, const int* __restrict__ dst,
                                                    int* __restrict__ histD, int* __restrict__ histS) {
    __shared__ int hD[NB], hS[NB];
    int tid = threadIdx.x;
    if (tid < NB) { hD[tid] = 0; hS[tid] = 0; }
    __syncthreads();
    int base = blockIdx.x * EPB;
    for (int i = tid; i < EPB; i += 256) {
        atomicAdd(&hD[dst[base + i] >> 10], 1);   // LDS atomic (CU-local)
        atomicAdd(&hS[src[base + i] >> 10], 1);
    }
    __syncthreads();
    if (tid < NB) {
        histD[blockIdx.x * NB + tid] = hD[tid];
        histS[blockIdx.x * NB + tid] = hS[tid];
    }
}

// ---- pass B: scan block-bucket matrices -> per-(block,bucket) offsets + coarse bases ----
__global__ __launch_bounds__(256) void scanB_kernel(const int* __restrict__ histD, const int* __restrict__ histS,
                                                    int* __restrict__ offD, int* __restrict__ offS,
                                                    int* __restrict__ coarseD, int* __restrict__ coarseS) {
    __shared__ int totD[NB], totS[NB], baseD[NB + 1], baseS[NB + 1];
    int t = threadIdx.x;
    if (t < NB) { int s = 0; for (int k = 0; k < PB; k++) s += histD[k * NB + t]; totD[t] = s; }
    else if (t >= 128 && t < 128 + NB) { int j = t - 128; int s = 0; for (int k = 0; k < PB; k++) s += histS[k * NB + j]; totS[j] = s; }
    __syncthreads();
    if (t == 0)   { int r = 0; for (int j = 0; j < NB; j++) { baseD[j] = r; r += totD[j]; } baseD[NB] = r; }
    if (t == 128) { int r = 0; for (int j = 0; j < NB; j++) { baseS[j] = r; r += totS[j]; } baseS[NB] = r; }
    __syncthreads();
    if (t < NB) { int r = baseD[t]; for (int k = 0; k < PB; k++) { offD[k * NB + t] = r; r += histD[k * NB + t]; } }
    else if (t >= 128 && t < 128 + NB) { int j = t - 128; int r = baseS[j]; for (int k = 0; k < PB; k++) { offS[k * NB + j] = r; r += histS[k * NB + j]; } }
    if (t <= NB) coarseD[t] = baseD[t];
    if (t >= 128 && t <= 128 + NB) coarseS[t - 128] = baseS[t - 128];
}

// ---- pass C: partition edges into coarse buckets (LDS cursors, disjoint global slices) ----
__global__ __launch_bounds__(256) void partC_kernel(const int* __restrict__ src, const int* __restrict__ dst,
                                                    const float* __restrict__ ew,
                                                    const int* __restrict__ offD, const int* __restrict__ offS,
                                                    int2* __restrict__ partD, int* __restrict__ partS) {
    __shared__ int cD[NB], cS[NB];
    int tid = threadIdx.x;
    if (tid < NB) { cD[tid] = offD[blockIdx.x * NB + tid]; cS[tid] = offS[blockIdx.x * NB + tid]; }
    __syncthreads();
    int base = blockIdx.x * EPB;
    for (int i = tid; i < EPB; i += 256) {
        int s = src[base + i], d = dst[base + i];
        float w = ew[base + i];
        int p = atomicAdd(&cD[d >> 10], 1);              // LDS atomic
        partD[p] = make_int2(s | ((d & 1023) << 17), __float_as_int(w));
        int q = atomicAdd(&cS[s >> 10], 1);              // LDS atomic
        partS[q] = s & 1023;
    }
}

// ---- pass D2: per src-bucket fine histogram -> outdeg_inv ----
__global__ __launch_bounds__(1024) void fineS_kernel(const int* __restrict__ partS, const int* __restrict__ coarseS,
                                                     float* __restrict__ outdeg_inv) {
    __shared__ int hist[1024];
    int tid = threadIdx.x;
    hist[tid] = 0;
    __syncthreads();
    int beg = coarseS[blockIdx.x], end = coarseS[blockIdx.x + 1];
    for (int i = beg + tid; i < end; i += 1024) atomicAdd(&hist[partS[i]], 1);
    __syncthreads();
    outdeg_inv[blockIdx.x * 1024 + tid] = 1.0f / sqrtf((float)max(hist[tid], 1));
}

// ---- pass D: per dst-bucket fine sort -> row_off, indeg_inv, final CSR (weights pre-scaled) ----
__global__ __launch_bounds__(1024) void fineD_kernel(const int2* __restrict__ partD, const int* __restrict__ coarseD,
                                                     const float* __restrict__ outdeg_inv,
                                                     int2* __restrict__ edge_perm, int* __restrict__ row_off,
                                                     float* __restrict__ indeg_inv) {
    __shared__ int hist[1024], cursor[1024];
    __shared__ int wsum[16];
    int tid = threadIdx.x, lane = tid & 63, wid = tid >> 6;
    hist[tid] = 0;
    __syncthreads();
    int beg = coarseD[blockIdx.x], end = coarseD[blockIdx.x + 1];
    for (int i = beg + tid; i < end; i += 1024) atomicAdd(&hist[(partD[i].x >> 17) & 1023], 1);
    __syncthreads();
    // exclusive scan of hist across the block
    int v = hist[tid];
    int x = v;
    #pragma unroll
    for (int s = 1; s < 64; s <<= 1) { int t = __shfl_up(x, s, 64); if (lane >= s) x += t; }
    if (lane == 63) wsum[wid] = x;
    __syncthreads();
    if (wid == 0) {
        int ws = (lane < 16) ? wsum[lane] : 0;
        int y = ws;
        #pragma unroll
        for (int s = 1; s < 16; s <<= 1) { int t = __shfl_up(y, s, 64); if (lane >= s) y += t; }
        if (lane < 16) wsum[lane] = y - ws;
    }
    __syncthreads();
    int ex = wsum[wid] + x - v;                 // exclusive scan value for this node
    cursor[tid] = beg + ex;
    int node = blockIdx.x * 1024 + tid;
    row_off[node] = beg + ex;
    indeg_inv[node] = 1.0f / sqrtf((float)max(v, 1));
    if (blockIdx.x == NB - 1 && tid == 0) row_off[N_NODES] = N_EDGES;
    __syncthreads();
    for (int i = beg + tid; i < end; i += 1024) {
        int2 t2 = partD[i];
        int d = (t2.x >> 17) & 1023, s = t2.x & 0x1FFFF;
        int p = atomicAdd(&cursor[d], 1);       // LDS atomic
        float w = __int_as_float(t2.y) * outdeg_inv[s];
        edge_perm[p] = make_int2(s, __float_as_int(w));
    }
}

// ---------------- register-tiled node transform: out = h @ W ----------------
template<int K, int C, int RN>
__global__ __launch_bounds__(256) void gemm_tile_kernel(
    const float* __restrict__ h, const float* __restrict__ W, float* __restrict__ out) {
    constexpr int BM = 64;
    constexpr int RM = 4;
    constexpr int KC = 64;
    constexpr int TX = C / RN;               // 16
    constexpr int TY = BM / RM;              // 16
    static_assert(TX * TY == 256, "bad tile");

    __shared__ float Ws[K * C];
    __shared__ float Hs[KC][BM + 4];

    const int tid = threadIdx.x;
    const long brow = (long)blockIdx.x * BM;

    for (int i = tid; i < K * C; i += 256) Ws[i] = W[i];

    const int tx = tid % TX;
    const int ty = tid / TX;
    float acc[RM][RN] = {};

    const int lr = tid % 16;
    const int lk = tid / 16;

    for (int kc = 0; kc < K; kc += KC) {
        __syncthreads();
        #pragma unroll
        for (int p0 = 0; p0 < BM; p0 += 16) {
            const int r = p0 + lr;
            const float4 hv = *(const float4*)(h + (brow + r) * K + kc + lk * 4);
            Hs[lk * 4 + 0][r] = hv.x;
            Hs[lk * 4 + 1][r] = hv.y;
            Hs[lk * 4 + 2][r] = hv.z;
            Hs[lk * 4 + 3][r] = hv.w;
        }
        __syncthreads();

        #pragma unroll
        for (int k = 0; k < KC; ++k) {
            const float4 a4 = *(const float4*)&Hs[k][ty * RM];
            const float av[RM] = {a4.x, a4.y, a4.z, a4.w};
            float b[RN];
            if constexpr (RN == 4) {
                *(float4*)b = *(const float4*)&Ws[(kc + k) * C + tx * RN];
            } else {
                *(float2*)b = *(const float2*)&Ws[(kc + k) * C + tx * RN];
            }
            #pragma unroll
            for (int i = 0; i < RM; ++i)
                #pragma unroll
                for (int j = 0; j < RN; ++j)
                    acc[i][j] += av[i] * b[j];
        }
    }

    #pragma unroll
    for (int i = 0; i < RM; ++i) {
        const long row = brow + ty * RM + i;
        if constexpr (RN == 4) {
            float4 v = {acc[i][0], acc[i][1], acc[i][2], acc[i][3]};
            *(float4*)(out + row * C + tx * RN) = v;
        } else {
            float2 v = {acc[i][0], acc[i][1]};
            *(float2*)(out + row * C + tx * RN) = v;
        }
    }
}

// ---------------- layer-0 aggregation + fused layer-1 transform ----------------
// One wave per node. Gather: lane = eslot(0..3) x chunk(0..15), 8 edges/iter (2 loads in
// flight). Epilogue: h1 = tanh(agg*sc + b0) held as chunk float4 on all lanes; then
// ht1[node] = h1 @ W1 (64->32) via shfl-broadcast of h1 + LDS W1 (2-way bank alias = free).
__global__ __launch_bounds__(256) void agg64_gemm_kernel(
    const float* __restrict__ ht, const int* __restrict__ row_off,
    const int2* __restrict__ ep, const float* __restrict__ indeg_inv,
    const float* __restrict__ b0, const float* __restrict__ W1,
    float* __restrict__ ht1, int N) {
    __shared__ float W1s[64 * 32];
    int tid = threadIdx.x;
    for (int i = tid; i < 64 * 32; i += 256) W1s[i] = W1[i];
    __syncthreads();

    int wave = (blockIdx.x * blockDim.x + tid) >> 6;
    int lane = tid & 63;
    if (wave >= N) return;
    int chunk = lane & 15;       // channels 4*chunk .. 4*chunk+3
    int eslot = lane >> 4;       // 0..3
    int beg = row_off[wave], end = row_off[wave + 1];

    float4 a0 = {0, 0, 0, 0}, a1 = {0, 0, 0, 0};
    for (int e = beg; e < end; e += 8) {
        int ei0 = e + eslot, ei1 = e + 4 + eslot;
        int2 d0 = ep[min(ei0, end - 1)];
        int2 d1 = ep[min(ei1, end - 1)];
        float w0 = (ei0 < end) ? __int_as_float(d0.y) : 0.0f;
        float w1 = (ei1 < end) ? __int_as_float(d1.y) : 0.0f;
        float4 h0 = *(const float4*)(ht + (long)d0.x * 64 + chunk * 4);
        float4 h1 = *(const float4*)(ht + (long)d1.x * 64 + chunk * 4);
        a0.x += h0.x * w0; a0.y += h0.y * w0; a0.z += h0.z * w0; a0.w += h0.w * w0;
        a1.x += h1.x * w1; a1.y += h1.y * w1; a1.z += h1.z * w1; a1.w += h1.w * w1;
    }
    a0.x += a1.x; a0.y += a1.y; a0.z += a1.z; a0.w += a1.w;
    // butterfly-reduce across eslot (lane bits 4,5); ALL lanes end with their chunk's sums
    #pragma unroll
    for (int s = 16; s <= 32; s <<= 1) {
        a0.x += __shfl_xor(a0.x, s, 64);
        a0.y += __shfl_xor(a0.y, s, 64);
        a0.z += __shfl_xor(a0.z, s, 64);
        a0.w += __shfl_xor(a0.w, s, 64);
    }
    float sc = indeg_inv[wave];
    float4 b = *(const float4*)(b0 + chunk * 4);
    float4 v;
    v.x = tanhf(a0.x * sc + b.x);
    v.y = tanhf(a0.y * sc + b.y);
    v.z = tanhf(a0.z * sc + b.z);
    v.w = tanhf(a0.w * sc + b.w);
    // fused 64->32: lane = (c, half); k in [32*half, 32*half+32)
    int c = lane & 31, half = lane >> 5;
    float t = 0.0f;
    #pragma unroll
    for (int j2 = 0; j2 < 8; ++j2) {
        int jj = half * 8 + j2;          // lane jj (0..15) holds channels 4jj..4jj+3
        float hx = __shfl(v.x, jj, 64);
        float hy = __shfl(v.y, jj, 64);
        float hz = __shfl(v.z, jj, 64);
        float hw = __shfl(v.w, jj, 64);
        int k = jj * 4;
        t += hx * W1s[(k + 0) * 32 + c];
        t += hy * W1s[(k + 1) * 32 + c];
        t += hz * W1s[(k + 2) * 32 + c];
        t += hw * W1s[(k + 3) * 32 + c];
    }
    t += __shfl_xor(t, 32, 64);
    if (half == 0) ht1[(long)wave * 32 + c] = t;
}

// C=32 agg + fused K=32->1 transform: lane = eslot(0..7) x chunk(0..7); 16 edges/iter
__global__ void agg32_dot_kernel(const float* __restrict__ ht, const int* __restrict__ row_off,
                                 const int2* __restrict__ ep,
                                 const float* __restrict__ indeg_inv, const float* __restrict__ bias,
                                 const float* __restrict__ W2, float* __restrict__ ht2, int N) {
    int wave = (blockIdx.x * blockDim.x + threadIdx.x) >> 6;
    int lane = threadIdx.x & 63;
    if (wave >= N) return;
    int chunk = lane & 7;        // channels 4*chunk .. 4*chunk+3
    int eslot = lane >> 3;       // 0..7
    int beg = row_off[wave], end = row_off[wave + 1];
    float4 a0 = {0, 0, 0, 0}, a1 = {0, 0, 0, 0};
    for (int e = beg; e < end; e += 16) {
        int ei0 = e + eslot, ei1 = e + 8 + eslot;
        int2 d0 = ep[min(ei0, end - 1)];
        int2 d1 = ep[min(ei1, end - 1)];
        float w0 = (ei0 < end) ? __int_as_float(d0.y) : 0.0f;
        float w1 = (ei1 < end) ? __int_as_float(d1.y) : 0.0f;
        float4 h0 = *(const float4*)(ht + (long)d0.x * 32 + chunk * 4);
        float4 h1 = *(const float4*)(ht + (long)d1.x * 32 + chunk * 4);
        a0.x += h0.x * w0; a0.y += h0.y * w0; a0.z += h0.z * w0; a0.w += h0.w * w0;
        a1.x += h1.x * w1; a1.y += h1.y * w1; a1.z += h1.z * w1; a1.w += h1.w * w1;
    }
    a0.x += a1.x; a0.y += a1.y; a0.z += a1.z; a0.w += a1.w;
    // butterfly-reduce across eslot (lane bits 3,4,5)
    #pragma unroll
    for (int s = 8; s <= 32; s <<= 1) {
        a0.x += __shfl_xor(a0.x, s, 64);
        a0.y += __shfl_xor(a0.y, s, 64);
        a0.z += __shfl_xor(a0.z, s, 64);
        a0.w += __shfl_xor(a0.w, s, 64);
    }
    float sc = indeg_inv[wave];
    float4 b = *(const float4*)(bias + chunk * 4);
    float4 w2 = *(const float4*)(W2 + chunk * 4);
    float t = tanhf(a0.x * sc + b.x) * w2.x
            + tanhf(a0.y * sc + b.y) * w2.y
            + tanhf(a0.z * sc + b.z) * w2.z
            + tanhf(a0.w * sc + b.w) * w2.w;
    t += __shfl_xor(t, 1, 64);
    t += __shfl_xor(t, 2, 64);
    t += __shfl_xor(t, 4, 64);
    if (lane == 0) ht2[wave] = t;
}

// C=1 final aggregation: 16 lanes per node (4 nodes/wave); coalesced edge reads
__global__ void agg1_kernel(const float* __restrict__ ht2, const int* __restrict__ row_off,
                            const int2* __restrict__ ep,
                            const float* __restrict__ indeg_inv, const float* __restrict__ bias,
                            float* __restrict__ out, int N) {
    int wave = (blockIdx.x * blockDim.x + threadIdx.x) >> 6;
    int lane = threadIdx.x & 63;
    int sub = lane >> 4;         // 0..3
    int slot = lane & 15;
    int node = wave * 4 + sub;
    if (node >= N) return;
    int beg = row_off[node], end = row_off[node + 1];
    float acc = 0.0f;
    for (int e = beg + slot; e < end; e += 16) {
        int2 t = ep[e];
        acc += ht2[t.x] * __int_as_float(t.y);
    }
    #pragma unroll
    for (int s = 1; s <= 8; s <<= 1) acc += __shfl_xor(acc, s, 64);  // within 16-lane group
    if (slot == 0) out[node] = acc * indeg_inv[node] + bias[0];
}

extern "C" void kernel_launch(void* const* d_in, const int* in_sizes, int n_in,
                              void* d_out, int out_size, void* d_ws, size_t ws_size,
                              hipStream_t stream) {
    const float* b_z = (const float*)d_in[0];
    const int*   src = (const int*)d_in[1];
    const int*   dst = (const int*)d_in[2];
    const float* ew  = (const float*)d_in[3];
    const float* W0 = (const float*)d_in[5];
    const float* b0 = (const float*)d_in[6];
    const float* W1 = (const float*)d_in[7];
    const float* b1 = (const float*)d_in[8];
    const float* W2 = (const float*)d_in[9];
    const float* b2 = (const float*)d_in[10];
    float* out = (float*)d_out;

    const int N = N_NODES;
    const int E = N_EDGES;

    // workspace layout (16B-aligned segments)
    char* p = (char*)d_ws;
    int*   row_off    = (int*)p;            p += (size_t)(N + 4) * 4;
    float* outdeg_inv = (float*)p;          p += (size_t)N * 4;
    float* indeg_inv  = (float*)p;          p += (size_t)N * 4;
    int*   histD      = (int*)p;            p += (size_t)PB * NB * 4;
    int*   histS      = (int*)p;            p += (size_t)PB * NB * 4;
    int*   offD       = (int*)p;            p += (size_t)PB * NB * 4;
    int*   offS       = (int*)p;            p += (size_t)PB * NB * 4;
    int*   coarseD    = (int*)p;            p += (size_t)(NB + 4) * 4;
    int*   coarseS    = (int*)p;            p += (size_t)(NB + 4) * 4;
    int2*  edge_perm  = (int2*)p;           p += (size_t)E * 8;
    float* bufA       = (float*)p;          p += (size_t)N * 64 * 4;
    float* bufB       = (float*)p;
    // aliases with disjoint lifetimes:
    int2*  partD = (int2*)bufA;   // dead after fineD; gemm0 then writes bufA
    int*   partS = (int*)bufB;    // dead after fineS; agg64_gemm then writes bufB (ht1)
    float* ht1   = bufB;          // N x 32, written by agg64_gemm, read by agg32_dot
    float* ht2   = bufA;          // N x 1, written by agg32_dot (bufA's ht dead by then)

    // ---- atomic-free CSR build (two-level counting sort) ----
    histA_kernel<<<PB, 256, 0, stream>>>(src, dst, histD, histS);
    scanB_kernel<<<1, 256, 0, stream>>>(histD, histS, offD, offS, coarseD, coarseS);
    partC_kernel<<<PB, 256, 0, stream>>>(src, dst, ew, offD, offS, partD, partS);
    fineS_kernel<<<NB, 1024, 0, stream>>>(partS, coarseS, outdeg_inv);
    fineD_kernel<<<NB, 1024, 0, stream>>>(partD, coarseD, outdeg_inv, edge_perm, row_off, indeg_inv);

    // ---- layer 0 transform: 128 -> 64 ----
    gemm_tile_kernel<128, 64, 4><<<N / 64, 256, 0, stream>>>(b_z, W0, bufA);

    // ---- layer 0 aggregation + tanh + fused layer-1 transform (64 -> 32) ----
    agg64_gemm_kernel<<<N / 4, 256, 0, stream>>>(bufA, row_off, edge_perm, indeg_inv, b0, W1, ht1, N);

    // ---- layer 1 aggregation + tanh + fused layer-2 transform (32 -> 1) ----
    agg32_dot_kernel<<<N / 4, 256, 0, stream>>>(ht1, row_off, edge_perm, indeg_inv, b1, W2, ht2, N);

    // ---- layer 2 aggregation -> out ----
    agg1_kernel<<<N / 16, 256, 0, stream>>>(ht2, row_off, edge_perm, indeg_inv, b2, out, N);
}

// Round 9
// 366.771 us; speedup vs baseline: 3.1099x; 1.0428x over previous
//
#include <hip/hip_runtime.h>
#include <math.h>

#define N_NODES 102400
#define N_EDGES 1638400
#define NB 100            // coarse buckets: node range 1024 (102400/1024)
#define PB 256            // partition blocks
#define EPB (N_EDGES/PB)  // 6400 edges per partition block

// ---- pass A: per-block coarse histograms of dst>>10 and src>>10 (LDS, atomic-free globally) ----
__global__ __launch_bounds__(256) void histA_kernel(const int* __restrict__ src, const int* __restrict__ dst,
                                                    int* __restrict__ histD, int* __restrict__ histS) {
    __shared__ int hD[NB], hS[NB];
    int tid = threadIdx.x;
    if (tid < NB) { hD[tid] = 0; hS[tid] = 0; }
    __syncthreads();
    int base = blockIdx.x * EPB;
    for (int i = tid; i < EPB; i += 256) {
        atomicAdd(&hD[dst[base + i] >> 10], 1);   // LDS atomic (CU-local)
        atomicAdd(&hS[src[base + i] >> 10], 1);
    }
    __syncthreads();
    if (tid < NB) {
        histD[blockIdx.x * NB + tid] = hD[tid];
        histS[blockIdx.x * NB + tid] = hS[tid];
    }
}

// ---- pass B: scan block-bucket matrices -> per-(block,bucket) offsets + coarse bases ----
__global__ __launch_bounds__(256) void scanB_kernel(const int* __restrict__ histD, const int* __restrict__ histS,
                                                    int* __restrict__ offD, int* __restrict__ offS,
                                                    int* __restrict__ coarseD, int* __restrict__ coarseS) {
    __shared__ int totD[NB], totS[NB], baseD[NB + 1], baseS[NB + 1];
    int t = threadIdx.x;
    if (t < NB) { int s = 0; for (int k = 0; k < PB; k++) s += histD[k * NB + t]; totD[t] = s; }
    else if (t >= 128 && t < 128 + NB) { int j = t - 128; int s = 0; for (int k = 0; k < PB; k++) s += histS[k * NB + j]; totS[j] = s; }
    __syncthreads();
    if (t == 0)   { int r = 0; for (int j = 0; j < NB; j++) { baseD[j] = r; r += totD[j]; } baseD[NB] = r; }
    if (t == 128) { int r = 0; for (int j = 0; j < NB; j++) { baseS[j] = r; r += totS[j]; } baseS[NB] = r; }
    __syncthreads();
    if (t < NB) { int r = baseD[t]; for (int k = 0; k < PB; k++) { offD[k * NB + t] = r; r += histD[k * NB + t]; } }
    else if (t >= 128 && t < 128 + NB) { int j = t - 128; int r = baseS[j]; for (int k = 0; k < PB; k++) { offS[k * NB + j] = r; r += histS[k * NB + j]; } }
    if (t <= NB) coarseD[t] = baseD[t];
    if (t >= 128 && t <= 128 + NB) coarseS[t - 128] = baseS[t - 128];
}

// ---- pass C: partition edges into coarse buckets (LDS cursors, disjoint global slices) ----
__global__ __launch_bounds__(256) void partC_kernel(const int* __restrict__ src, const int* __restrict__ dst,
                                                    const float* __restrict__ ew,
                                                    const int* __restrict__ offD, const int* __restrict__ offS,
                                                    int2* __restrict__ partD, int* __restrict__ partS) {
    __shared__ int cD[NB], cS[NB];
    int tid = threadIdx.x;
    if (tid < NB) { cD[tid] = offD[blockIdx.x * NB + tid]; cS[tid] = offS[blockIdx.x * NB + tid]; }
    __syncthreads();
    int base = blockIdx.x * EPB;
    for (int i = tid; i < EPB; i += 256) {
        int s = src[base + i], d = dst[base + i];
        float w = ew[base + i];
        int p = atomicAdd(&cD[d >> 10], 1);              // LDS atomic
        partD[p] = make_int2(s | ((d & 1023) << 17), __float_as_int(w));
        int q = atomicAdd(&cS[s >> 10], 1);              // LDS atomic
        partS[q] = s & 1023;
    }
}

// ---- pass D2: per src-bucket fine histogram -> outdeg_inv ----
__global__ __launch_bounds__(1024) void fineS_kernel(const int* __restrict__ partS, const int* __restrict__ coarseS,
                                                     float* __restrict__ outdeg_inv) {
    __shared__ int hist[1024];
    int tid = threadIdx.x;
    hist[tid] = 0;
    __syncthreads();
    int beg = coarseS[blockIdx.x], end = coarseS[blockIdx.x + 1];
    for (int i = beg + tid; i < end; i += 1024) atomicAdd(&hist[partS[i]], 1);
    __syncthreads();
    outdeg_inv[blockIdx.x * 1024 + tid] = 1.0f / sqrtf((float)max(hist[tid], 1));
}

// ---- pass D: per dst-bucket fine sort -> row_off, indeg_inv, final CSR (weights pre-scaled) ----
__global__ __launch_bounds__(1024) void fineD_kernel(const int2* __restrict__ partD, const int* __restrict__ coarseD,
                                                     const float* __restrict__ outdeg_inv,
                                                     int2* __restrict__ edge_perm, int* __restrict__ row_off,
                                                     float* __restrict__ indeg_inv) {
    __shared__ int hist[1024], cursor[1024];
    __shared__ int wsum[16];
    int tid = threadIdx.x, lane = tid & 63, wid = tid >> 6;
    hist[tid] = 0;
    __syncthreads();
    int beg = coarseD[blockIdx.x], end = coarseD[blockIdx.x + 1];
    for (int i = beg + tid; i < end; i += 1024) atomicAdd(&hist[(partD[i].x >> 17) & 1023], 1);
    __syncthreads();
    // exclusive scan of hist across the block
    int v = hist[tid];
    int x = v;
    #pragma unroll
    for (int s = 1; s < 64; s <<= 1) { int t = __shfl_up(x, s, 64); if (lane >= s) x += t; }
    if (lane == 63) wsum[wid] = x;
    __syncthreads();
    if (wid == 0) {
        int ws = (lane < 16) ? wsum[lane] : 0;
        int y = ws;
        #pragma unroll
        for (int s = 1; s < 16; s <<= 1) { int t = __shfl_up(y, s, 64); if (lane >= s) y += t; }
        if (lane < 16) wsum[lane] = y - ws;
    }
    __syncthreads();
    int ex = wsum[wid] + x - v;                 // exclusive scan value for this node
    cursor[tid] = beg + ex;
    int node = blockIdx.x * 1024 + tid;
    row_off[node] = beg + ex;
    indeg_inv[node] = 1.0f / sqrtf((float)max(v, 1));
    if (blockIdx.x == NB - 1 && tid == 0) row_off[N_NODES] = N_EDGES;
    __syncthreads();
    for (int i = beg + tid; i < end; i += 1024) {
        int2 t2 = partD[i];
        int d = (t2.x >> 17) & 1023, s = t2.x & 0x1FFFF;
        int p = atomicAdd(&cursor[d], 1);       // LDS atomic
        float w = __int_as_float(t2.y) * outdeg_inv[s];
        edge_perm[p] = make_int2(s, __float_as_int(w));
    }
}

// ---------------- register-tiled node transform: out = h @ W ----------------
template<int K, int C, int RN>
__global__ __launch_bounds__(256) void gemm_tile_kernel(
    const float* __restrict__ h, const float* __restrict__ W, float* __restrict__ out) {
    constexpr int BM = 64;
    constexpr int RM = 4;
    constexpr int KC = 64;
    constexpr int TX = C / RN;               // 16
    constexpr int TY = BM / RM;              // 16
    static_assert(TX * TY == 256, "bad tile");

    __shared__ float Ws[K * C];
    __shared__ float Hs[KC][BM + 4];

    const int tid = threadIdx.x;
    const long brow = (long)blockIdx.x * BM;

    for (int i = tid; i < K * C; i += 256) Ws[i] = W[i];

    const int tx = tid % TX;
    const int ty = tid / TX;
    float acc[RM][RN] = {};

    const int lr = tid % 16;
    const int lk = tid / 16;

    for (int kc = 0; kc < K; kc += KC) {
        __syncthreads();
        #pragma unroll
        for (int p0 = 0; p0 < BM; p0 += 16) {
            const int r = p0 + lr;
            const float4 hv = *(const float4*)(h + (brow + r) * K + kc + lk * 4);
            Hs[lk * 4 + 0][r] = hv.x;
            Hs[lk * 4 + 1][r] = hv.y;
            Hs[lk * 4 + 2][r] = hv.z;
            Hs[lk * 4 + 3][r] = hv.w;
        }
        __syncthreads();

        #pragma unroll
        for (int k = 0; k < KC; ++k) {
            const float4 a4 = *(const float4*)&Hs[k][ty * RM];
            const float av[RM] = {a4.x, a4.y, a4.z, a4.w};
            float b[RN];
            if constexpr (RN == 4) {
                *(float4*)b = *(const float4*)&Ws[(kc + k) * C + tx * RN];
            } else {
                *(float2*)b = *(const float2*)&Ws[(kc + k) * C + tx * RN];
            }
            #pragma unroll
            for (int i = 0; i < RM; ++i)
                #pragma unroll
                for (int j = 0; j < RN; ++j)
                    acc[i][j] += av[i] * b[j];
        }
    }

    #pragma unroll
    for (int i = 0; i < RM; ++i) {
        const long row = brow + ty * RM + i;
        if constexpr (RN == 4) {
            float4 v = {acc[i][0], acc[i][1], acc[i][2], acc[i][3]};
            *(float4*)(out + row * C + tx * RN) = v;
        } else {
            float2 v = {acc[i][0], acc[i][1]};
            *(float2*)(out + row * C + tx * RN) = v;
        }
    }
}

// ---------------- layer-0 aggregation + fused layer-1 transform ----------------
// One wave per node. Gather: lane = eslot(0..3) x chunk(0..15), 8 edges/iter (2 loads in
// flight). Epilogue v2: h1 = tanh(agg*sc + b0) goes through a per-wave LDS row (one
// ds_write_b128), then ht1 = h1 @ W1 via broadcast ds_read_b128 (h1) + stride-1 ds_read
// (W1, 2-way alias = free). No ds_permute chains.
__global__ __launch_bounds__(256) void agg64_gemm_kernel(
    const float* __restrict__ ht, const int* __restrict__ row_off,
    const int2* __restrict__ ep, const float* __restrict__ indeg_inv,
    const float* __restrict__ b0, const float* __restrict__ W1,
    float* __restrict__ ht1, int N) {
    __shared__ float W1s[64 * 32];
    __shared__ float h1s[4][64];
    int tid = threadIdx.x;
    {   // vectorized W1 staging: 2 x float4 per thread
        const float4* W1v = (const float4*)W1;
        float4* W1sv = (float4*)W1s;
        W1sv[tid] = W1v[tid];
        W1sv[tid + 256] = W1v[tid + 256];
    }
    __syncthreads();

    int wave = (blockIdx.x * blockDim.x + tid) >> 6;
    int lane = tid & 63;
    if (wave >= N) return;
    int chunk = lane & 15;       // channels 4*chunk .. 4*chunk+3
    int eslot = lane >> 4;       // 0..3
    int beg = row_off[wave], end = row_off[wave + 1];

    float4 a0 = {0, 0, 0, 0}, a1 = {0, 0, 0, 0};
    for (int e = beg; e < end; e += 8) {
        int ei0 = e + eslot, ei1 = e + 4 + eslot;
        int2 d0 = ep[min(ei0, end - 1)];
        int2 d1 = ep[min(ei1, end - 1)];
        float w0 = (ei0 < end) ? __int_as_float(d0.y) : 0.0f;
        float w1 = (ei1 < end) ? __int_as_float(d1.y) : 0.0f;
        float4 h0 = *(const float4*)(ht + (long)d0.x * 64 + chunk * 4);
        float4 h1 = *(const float4*)(ht + (long)d1.x * 64 + chunk * 4);
        a0.x += h0.x * w0; a0.y += h0.y * w0; a0.z += h0.z * w0; a0.w += h0.w * w0;
        a1.x += h1.x * w1; a1.y += h1.y * w1; a1.z += h1.z * w1; a1.w += h1.w * w1;
    }
    a0.x += a1.x; a0.y += a1.y; a0.z += a1.z; a0.w += a1.w;
    // butterfly-reduce across eslot (lane bits 4,5)
    #pragma unroll
    for (int s = 16; s <= 32; s <<= 1) {
        a0.x += __shfl_xor(a0.x, s, 64);
        a0.y += __shfl_xor(a0.y, s, 64);
        a0.z += __shfl_xor(a0.z, s, 64);
        a0.w += __shfl_xor(a0.w, s, 64);
    }
    int wv = tid >> 6;
    if (eslot == 0) {
        float sc = indeg_inv[wave];
        float4 b = *(const float4*)(b0 + chunk * 4);
        float4 v;
        v.x = tanhf(a0.x * sc + b.x);
        v.y = tanhf(a0.y * sc + b.y);
        v.z = tanhf(a0.z * sc + b.z);
        v.w = tanhf(a0.w * sc + b.w);
        *(float4*)&h1s[wv][chunk * 4] = v;   // one ds_write_b128, banks 2-way (free)
    }
    // fused 64->32: lane = (c, half); k in [32*half, 32*half+32)
    // (wave-synchronous LDS RAW; compiler inserts lgkmcnt wait)
    int c = lane & 31, half = lane >> 5;
    float t = 0.0f;
    #pragma unroll
    for (int j4 = 0; j4 < 8; ++j4) {
        int k = half * 32 + j4 * 4;
        float4 hh = *(const float4*)&h1s[wv][k];    // broadcast read (2 addrs/wave)
        t += hh.x * W1s[(k + 0) * 32 + c];
        t += hh.y * W1s[(k + 1) * 32 + c];
        t += hh.z * W1s[(k + 2) * 32 + c];
        t += hh.w * W1s[(k + 3) * 32 + c];
    }
    t += __shfl_xor(t, 32, 64);
    if (half == 0) ht1[(long)wave * 32 + c] = t;
}

// C=32 agg + fused K=32->1 transform: lane = eslot(0..7) x chunk(0..7); 16 edges/iter
__global__ void agg32_dot_kernel(const float* __restrict__ ht, const int* __restrict__ row_off,
                                 const int2* __restrict__ ep,
                                 const float* __restrict__ indeg_inv, const float* __restrict__ bias,
                                 const float* __restrict__ W2, float* __restrict__ ht2, int N) {
    int wave = (blockIdx.x * blockDim.x + threadIdx.x) >> 6;
    int lane = threadIdx.x & 63;
    if (wave >= N) return;
    int chunk = lane & 7;        // channels 4*chunk .. 4*chunk+3
    int eslot = lane >> 3;       // 0..7
    int beg = row_off[wave], end = row_off[wave + 1];
    float4 a0 = {0, 0, 0, 0}, a1 = {0, 0, 0, 0};
    for (int e = beg; e < end; e += 16) {
        int ei0 = e + eslot, ei1 = e + 8 + eslot;
        int2 d0 = ep[min(ei0, end - 1)];
        int2 d1 = ep[min(ei1, end - 1)];
        float w0 = (ei0 < end) ? __int_as_float(d0.y) : 0.0f;
        float w1 = (ei1 < end) ? __int_as_float(d1.y) : 0.0f;
        float4 h0 = *(const float4*)(ht + (long)d0.x * 32 + chunk * 4);
        float4 h1 = *(const float4*)(ht + (long)d1.x * 32 + chunk * 4);
        a0.x += h0.x * w0; a0.y += h0.y * w0; a0.z += h0.z * w0; a0.w += h0.w * w0;
        a1.x += h1.x * w1; a1.y += h1.y * w1; a1.z += h1.z * w1; a1.w += h1.w * w1;
    }
    a0.x += a1.x; a0.y += a1.y; a0.z += a1.z; a0.w += a1.w;
    // butterfly-reduce across eslot (lane bits 3,4,5)
    #pragma unroll
    for (int s = 8; s <= 32; s <<= 1) {
        a0.x += __shfl_xor(a0.x, s, 64);
        a0.y += __shfl_xor(a0.y, s, 64);
        a0.z += __shfl_xor(a0.z, s, 64);
        a0.w += __shfl_xor(a0.w, s, 64);
    }
    float sc = indeg_inv[wave];
    float4 b = *(const float4*)(bias + chunk * 4);
    float4 w2 = *(const float4*)(W2 + chunk * 4);
    float t = tanhf(a0.x * sc + b.x) * w2.x
            + tanhf(a0.y * sc + b.y) * w2.y
            + tanhf(a0.z * sc + b.z) * w2.z
            + tanhf(a0.w * sc + b.w) * w2.w;
    t += __shfl_xor(t, 1, 64);
    t += __shfl_xor(t, 2, 64);
    t += __shfl_xor(t, 4, 64);
    if (lane == 0) ht2[wave] = t;
}

// C=1 final aggregation: 16 lanes per node (4 nodes/wave); coalesced edge reads
__global__ void agg1_kernel(const float* __restrict__ ht2, const int* __restrict__ row_off,
                            const int2* __restrict__ ep,
                            const float* __restrict__ indeg_inv, const float* __restrict__ bias,
                            float* __restrict__ out, int N) {
    int wave = (blockIdx.x * blockDim.x + threadIdx.x) >> 6;
    int lane = threadIdx.x & 63;
    int sub = lane >> 4;         // 0..3
    int slot = lane & 15;
    int node = wave * 4 + sub;
    if (node >= N) return;
    int beg = row_off[node], end = row_off[node + 1];
    float acc = 0.0f;
    for (int e = beg + slot; e < end; e += 16) {
        int2 t = ep[e];
        acc += ht2[t.x] * __int_as_float(t.y);
    }
    #pragma unroll
    for (int s = 1; s <= 8; s <<= 1) acc += __shfl_xor(acc, s, 64);  // within 16-lane group
    if (slot == 0) out[node] = acc * indeg_inv[node] + bias[0];
}

extern "C" void kernel_launch(void* const* d_in, const int* in_sizes, int n_in,
                              void* d_out, int out_size, void* d_ws, size_t ws_size,
                              hipStream_t stream) {
    const float* b_z = (const float*)d_in[0];
    const int*   src = (const int*)d_in[1];
    const int*   dst = (const int*)d_in[2];
    const float* ew  = (const float*)d_in[3];
    const float* W0 = (const float*)d_in[5];
    const float* b0 = (const float*)d_in[6];
    const float* W1 = (const float*)d_in[7];
    const float* b1 = (const float*)d_in[8];
    const float* W2 = (const float*)d_in[9];
    const float* b2 = (const float*)d_in[10];
    float* out = (float*)d_out;

    const int N = N_NODES;
    const int E = N_EDGES;

    // workspace layout (16B-aligned segments)
    char* p = (char*)d_ws;
    int*   row_off    = (int*)p;            p += (size_t)(N + 4) * 4;
    float* outdeg_inv = (float*)p;          p += (size_t)N * 4;
    float* indeg_inv  = (float*)p;          p += (size_t)N * 4;
    int*   histD      = (int*)p;            p += (size_t)PB * NB * 4;
    int*   histS      = (int*)p;            p += (size_t)PB * NB * 4;
    int*   offD       = (int*)p;            p += (size_t)PB * NB * 4;
    int*   offS       = (int*)p;            p += (size_t)PB * NB * 4;
    int*   coarseD    = (int*)p;            p += (size_t)(NB + 4) * 4;
    int*   coarseS    = (int*)p;            p += (size_t)(NB + 4) * 4;
    int2*  edge_perm  = (int2*)p;           p += (size_t)E * 8;
    float* bufA       = (float*)p;          p += (size_t)N * 64 * 4;
    float* bufB       = (float*)p;
    // aliases with disjoint lifetimes:
    int2*  partD = (int2*)bufA;   // dead after fineD; gemm0 then writes bufA
    int*   partS = (int*)bufB;    // dead after fineS; agg64_gemm then writes bufB (ht1)
    float* ht1   = bufB;          // N x 32, written by agg64_gemm, read by agg32_dot
    float* ht2   = bufA;          // N x 1, written by agg32_dot (bufA's ht dead by then)

    // ---- atomic-free CSR build (two-level counting sort) ----
    histA_kernel<<<PB, 256, 0, stream>>>(src, dst, histD, histS);
    scanB_kernel<<<1, 256, 0, stream>>>(histD, histS, offD, offS, coarseD, coarseS);
    partC_kernel<<<PB, 256, 0, stream>>>(src, dst, ew, offD, offS, partD, partS);
    fineS_kernel<<<NB, 1024, 0, stream>>>(partS, coarseS, outdeg_inv);
    fineD_kernel<<<NB, 1024, 0, stream>>>(partD, coarseD, outdeg_inv, edge_perm, row_off, indeg_inv);

    // ---- layer 0 transform: 128 -> 64 ----
    gemm_tile_kernel<128, 64, 4><<<N / 64, 256, 0, stream>>>(b_z, W0, bufA);

    // ---- layer 0 aggregation + tanh + fused layer-1 transform (64 -> 32) ----
    agg64_gemm_kernel<<<N / 4, 256, 0, stream>>>(bufA, row_off, edge_perm, indeg_inv, b0, W1, ht1, N);

    // ---- layer 1 aggregation + tanh + fused layer-2 transform (32 -> 1) ----
    agg32_dot_kernel<<<N / 4, 256, 0, stream>>>(ht1, row_off, edge_perm, indeg_inv, b1, W2, ht2, N);

    // ---- layer 2 aggregation -> out ----
    agg1_kernel<<<N / 16, 256, 0, stream>>>(ht2, row_off, edge_perm, indeg_inv, b2, out, N);
}

// Round 10
// 340.841 us; speedup vs baseline: 3.3465x; 1.0761x over previous
//
#include <hip/hip_runtime.h>
#include <hip/hip_fp16.h>
#include <math.h>

#define N_NODES 102400
#define N_EDGES 1638400
#define NB 100            // coarse buckets: node range 1024 (102400/1024)
#define PB 256            // partition blocks
#define EPB (N_EDGES/PB)  // 6400 edges per partition block

// ---- pass A: per-block coarse histograms of dst>>10 and src>>10 (LDS, atomic-free globally) ----
__global__ __launch_bounds__(256) void histA_kernel(const int* __restrict__ src, const int* __restrict__ dst,
                                                    int* __restrict__ histD, int* __restrict__ histS) {
    __shared__ int hD[NB], hS[NB];
    int tid = threadIdx.x;
    if (tid < NB) { hD[tid] = 0; hS[tid] = 0; }
    __syncthreads();
    int base = blockIdx.x * EPB;
    for (int i = tid; i < EPB; i += 256) {
        atomicAdd(&hD[dst[base + i] >> 10], 1);   // LDS atomic (CU-local)
        atomicAdd(&hS[src[base + i] >> 10], 1);
    }
    __syncthreads();
    if (tid < NB) {
        histD[blockIdx.x * NB + tid] = hD[tid];
        histS[blockIdx.x * NB + tid] = hS[tid];
    }
}

// ---- pass B: scan block-bucket matrices -> per-(block,bucket) offsets + coarse bases ----
__global__ __launch_bounds__(256) void scanB_kernel(const int* __restrict__ histD, const int* __restrict__ histS,
                                                    int* __restrict__ offD, int* __restrict__ offS,
                                                    int* __restrict__ coarseD, int* __restrict__ coarseS) {
    __shared__ int totD[NB], totS[NB], baseD[NB + 1], baseS[NB + 1];
    int t = threadIdx.x;
    if (t < NB) { int s = 0; for (int k = 0; k < PB; k++) s += histD[k * NB + t]; totD[t] = s; }
    else if (t >= 128 && t < 128 + NB) { int j = t - 128; int s = 0; for (int k = 0; k < PB; k++) s += histS[k * NB + j]; totS[j] = s; }
    __syncthreads();
    if (t == 0)   { int r = 0; for (int j = 0; j < NB; j++) { baseD[j] = r; r += totD[j]; } baseD[NB] = r; }
    if (t == 128) { int r = 0; for (int j = 0; j < NB; j++) { baseS[j] = r; r += totS[j]; } baseS[NB] = r; }
    __syncthreads();
    if (t < NB) { int r = baseD[t]; for (int k = 0; k < PB; k++) { offD[k * NB + t] = r; r += histD[k * NB + t]; } }
    else if (t >= 128 && t < 128 + NB) { int j = t - 128; int r = baseS[j]; for (int k = 0; k < PB; k++) { offS[k * NB + j] = r; r += histS[k * NB + j]; } }
    if (t <= NB) coarseD[t] = baseD[t];
    if (t >= 128 && t <= 128 + NB) coarseS[t - 128] = baseS[t - 128];
}

// ---- pass C: partition edges into coarse buckets (LDS cursors, disjoint global slices) ----
__global__ __launch_bounds__(256) void partC_kernel(const int* __restrict__ src, const int* __restrict__ dst,
                                                    const float* __restrict__ ew,
                                                    const int* __restrict__ offD, const int* __restrict__ offS,
                                                    int2* __restrict__ partD, int* __restrict__ partS) {
    __shared__ int cD[NB], cS[NB];
    int tid = threadIdx.x;
    if (tid < NB) { cD[tid] = offD[blockIdx.x * NB + tid]; cS[tid] = offS[blockIdx.x * NB + tid]; }
    __syncthreads();
    int base = blockIdx.x * EPB;
    for (int i = tid; i < EPB; i += 256) {
        int s = src[base + i], d = dst[base + i];
        float w = ew[base + i];
        int p = atomicAdd(&cD[d >> 10], 1);              // LDS atomic
        partD[p] = make_int2(s | ((d & 1023) << 17), __float_as_int(w));
        int q = atomicAdd(&cS[s >> 10], 1);              // LDS atomic
        partS[q] = s & 1023;
    }
}

// ---- pass D2: per src-bucket fine histogram -> outdeg_inv ----
__global__ __launch_bounds__(1024) void fineS_kernel(const int* __restrict__ partS, const int* __restrict__ coarseS,
                                                     float* __restrict__ outdeg_inv) {
    __shared__ int hist[1024];
    int tid = threadIdx.x;
    hist[tid] = 0;
    __syncthreads();
    int beg = coarseS[blockIdx.x], end = coarseS[blockIdx.x + 1];
    for (int i = beg + tid; i < end; i += 1024) atomicAdd(&hist[partS[i]], 1);
    __syncthreads();
    outdeg_inv[blockIdx.x * 1024 + tid] = 1.0f / sqrtf((float)max(hist[tid], 1));
}

// ---- pass D: per dst-bucket fine sort -> row_off, indeg_inv, final CSR (weights pre-scaled) ----
__global__ __launch_bounds__(1024) void fineD_kernel(const int2* __restrict__ partD, const int* __restrict__ coarseD,
                                                     const float* __restrict__ outdeg_inv,
                                                     int2* __restrict__ edge_perm, int* __restrict__ row_off,
                                                     float* __restrict__ indeg_inv) {
    __shared__ int hist[1024], cursor[1024];
    __shared__ int wsum[16];
    int tid = threadIdx.x, lane = tid & 63, wid = tid >> 6;
    hist[tid] = 0;
    __syncthreads();
    int beg = coarseD[blockIdx.x], end = coarseD[blockIdx.x + 1];
    for (int i = beg + tid; i < end; i += 1024) atomicAdd(&hist[(partD[i].x >> 17) & 1023], 1);
    __syncthreads();
    // exclusive scan of hist across the block
    int v = hist[tid];
    int x = v;
    #pragma unroll
    for (int s = 1; s < 64; s <<= 1) { int t = __shfl_up(x, s, 64); if (lane >= s) x += t; }
    if (lane == 63) wsum[wid] = x;
    __syncthreads();
    if (wid == 0) {
        int ws = (lane < 16) ? wsum[lane] : 0;
        int y = ws;
        #pragma unroll
        for (int s = 1; s < 16; s <<= 1) { int t = __shfl_up(y, s, 64); if (lane >= s) y += t; }
        if (lane < 16) wsum[lane] = y - ws;
    }
    __syncthreads();
    int ex = wsum[wid] + x - v;                 // exclusive scan value for this node
    cursor[tid] = beg + ex;
    int node = blockIdx.x * 1024 + tid;
    row_off[node] = beg + ex;
    indeg_inv[node] = 1.0f / sqrtf((float)max(v, 1));
    if (blockIdx.x == NB - 1 && tid == 0) row_off[N_NODES] = N_EDGES;
    __syncthreads();
    for (int i = beg + tid; i < end; i += 1024) {
        int2 t2 = partD[i];
        int d = (t2.x >> 17) & 1023, s = t2.x & 0x1FFFF;
        int p = atomicAdd(&cursor[d], 1);       // LDS atomic
        float w = __int_as_float(t2.y) * outdeg_inv[s];
        edge_perm[p] = make_int2(s, __float_as_int(w));
    }
}

// ---------------- register-tiled node transform: out(fp16) = h @ W ----------------
template<int K, int C, int RN>
__global__ __launch_bounds__(256) void gemm_tile_kernel(
    const float* __restrict__ h, const float* __restrict__ W, __half* __restrict__ out) {
    constexpr int BM = 64;
    constexpr int RM = 4;
    constexpr int KC = 64;
    constexpr int TX = C / RN;               // 16
    constexpr int TY = BM / RM;              // 16
    static_assert(TX * TY == 256, "bad tile");
    static_assert(RN == 4, "fp16 epilogue assumes RN==4");

    __shared__ float Ws[K * C];
    __shared__ float Hs[KC][BM + 4];

    const int tid = threadIdx.x;
    const long brow = (long)blockIdx.x * BM;

    for (int i = tid; i < K * C; i += 256) Ws[i] = W[i];

    const int tx = tid % TX;
    const int ty = tid / TX;
    float acc[RM][RN] = {};

    const int lr = tid % 16;
    const int lk = tid / 16;

    for (int kc = 0; kc < K; kc += KC) {
        __syncthreads();
        #pragma unroll
        for (int p0 = 0; p0 < BM; p0 += 16) {
            const int r = p0 + lr;
            const float4 hv = *(const float4*)(h + (brow + r) * K + kc + lk * 4);
            Hs[lk * 4 + 0][r] = hv.x;
            Hs[lk * 4 + 1][r] = hv.y;
            Hs[lk * 4 + 2][r] = hv.z;
            Hs[lk * 4 + 3][r] = hv.w;
        }
        __syncthreads();

        #pragma unroll
        for (int k = 0; k < KC; ++k) {
            const float4 a4 = *(const float4*)&Hs[k][ty * RM];
            const float av[RM] = {a4.x, a4.y, a4.z, a4.w};
            float b[RN];
            *(float4*)b = *(const float4*)&Ws[(kc + k) * C + tx * RN];
            #pragma unroll
            for (int i = 0; i < RM; ++i)
                #pragma unroll
                for (int j = 0; j < RN; ++j)
                    acc[i][j] += av[i] * b[j];
        }
    }

    #pragma unroll
    for (int i = 0; i < RM; ++i) {
        const long row = brow + ty * RM + i;
        __half2 p01 = __floats2half2_rn(acc[i][0], acc[i][1]);
        __half2 p23 = __floats2half2_rn(acc[i][2], acc[i][3]);
        int2 packed = make_int2(*(int*)&p01, *(int*)&p23);
        *(int2*)(out + row * C + tx * RN) = packed;   // 8B coalesced store
    }
}

// ---------------- layer-0 aggregation (fp16 gather) + fused layer-1 transform ----------------
// One wave per node. lane = eslot(0..3) x chunk(0..15); each lane loads 4 halves (8B) of
// its edge's src row (row = 128B). 8 edges/iter (2 loads in flight). fp32 accumulate.
// Epilogue: h1 = tanh(agg*sc + b0) -> per-wave LDS row -> ht1 = h1 @ W1 (64->32) -> fp16.
__global__ __launch_bounds__(256) void agg64_gemm_kernel(
    const __half* __restrict__ ht, const int* __restrict__ row_off,
    const int2* __restrict__ ep, const float* __restrict__ indeg_inv,
    const float* __restrict__ b0, const float* __restrict__ W1,
    __half* __restrict__ ht1, int N) {
    __shared__ float W1s[64 * 32];
    __shared__ float h1s[4][64];
    int tid = threadIdx.x;
    {   // vectorized W1 staging: 2 x float4 per thread
        const float4* W1v = (const float4*)W1;
        float4* W1sv = (float4*)W1s;
        W1sv[tid] = W1v[tid];
        W1sv[tid + 256] = W1v[tid + 256];
    }
    __syncthreads();

    int wave = (blockIdx.x * blockDim.x + tid) >> 6;
    int lane = tid & 63;
    if (wave >= N) return;
    int chunk = lane & 15;       // channels 4*chunk .. 4*chunk+3
    int eslot = lane >> 4;       // 0..3
    int beg = row_off[wave], end = row_off[wave + 1];

    float4 a0 = {0, 0, 0, 0}, a1 = {0, 0, 0, 0};
    for (int e = beg; e < end; e += 8) {
        int ei0 = e + eslot, ei1 = e + 4 + eslot;
        int2 d0 = ep[min(ei0, end - 1)];
        int2 d1 = ep[min(ei1, end - 1)];
        float w0 = (ei0 < end) ? __int_as_float(d0.y) : 0.0f;
        float w1 = (ei1 < end) ? __int_as_float(d1.y) : 0.0f;
        int2 r0 = *(const int2*)(ht + (long)d0.x * 64 + chunk * 4);
        int2 r1 = *(const int2*)(ht + (long)d1.x * 64 + chunk * 4);
        float2 f0a = __half22float2(*(__half2*)&r0.x);
        float2 f0b = __half22float2(*(__half2*)&r0.y);
        float2 f1a = __half22float2(*(__half2*)&r1.x);
        float2 f1b = __half22float2(*(__half2*)&r1.y);
        a0.x += f0a.x * w0; a0.y += f0a.y * w0; a0.z += f0b.x * w0; a0.w += f0b.y * w0;
        a1.x += f1a.x * w1; a1.y += f1a.y * w1; a1.z += f1b.x * w1; a1.w += f1b.y * w1;
    }
    a0.x += a1.x; a0.y += a1.y; a0.z += a1.z; a0.w += a1.w;
    // butterfly-reduce across eslot (lane bits 4,5)
    #pragma unroll
    for (int s = 16; s <= 32; s <<= 1) {
        a0.x += __shfl_xor(a0.x, s, 64);
        a0.y += __shfl_xor(a0.y, s, 64);
        a0.z += __shfl_xor(a0.z, s, 64);
        a0.w += __shfl_xor(a0.w, s, 64);
    }
    int wv = tid >> 6;
    if (eslot == 0) {
        float sc = indeg_inv[wave];
        float4 b = *(const float4*)(b0 + chunk * 4);
        float4 v;
        v.x = tanhf(a0.x * sc + b.x);
        v.y = tanhf(a0.y * sc + b.y);
        v.z = tanhf(a0.z * sc + b.z);
        v.w = tanhf(a0.w * sc + b.w);
        *(float4*)&h1s[wv][chunk * 4] = v;   // one ds_write_b128
    }
    // fused 64->32: lane = (c, half); k in [32*half, 32*half+32)
    int c = lane & 31, half = lane >> 5;
    float t = 0.0f;
    #pragma unroll
    for (int j4 = 0; j4 < 8; ++j4) {
        int k = half * 32 + j4 * 4;
        float4 hh = *(const float4*)&h1s[wv][k];    // broadcast read
        t += hh.x * W1s[(k + 0) * 32 + c];
        t += hh.y * W1s[(k + 1) * 32 + c];
        t += hh.z * W1s[(k + 2) * 32 + c];
        t += hh.w * W1s[(k + 3) * 32 + c];
    }
    t += __shfl_xor(t, 32, 64);
    if (half == 0) ht1[(long)wave * 32 + c] = __float2half_rn(t);
}

// C=32 agg (fp16 gather) + fused K=32->1 transform: lane = eslot(0..7) x chunk(0..7)
__global__ void agg32_dot_kernel(const __half* __restrict__ ht, const int* __restrict__ row_off,
                                 const int2* __restrict__ ep,
                                 const float* __restrict__ indeg_inv, const float* __restrict__ bias,
                                 const float* __restrict__ W2, float* __restrict__ ht2, int N) {
    int wave = (blockIdx.x * blockDim.x + threadIdx.x) >> 6;
    int lane = threadIdx.x & 63;
    if (wave >= N) return;
    int chunk = lane & 7;        // channels 4*chunk .. 4*chunk+3
    int eslot = lane >> 3;       // 0..7
    int beg = row_off[wave], end = row_off[wave + 1];
    float4 a0 = {0, 0, 0, 0}, a1 = {0, 0, 0, 0};
    for (int e = beg; e < end; e += 16) {
        int ei0 = e + eslot, ei1 = e + 8 + eslot;
        int2 d0 = ep[min(ei0, end - 1)];
        int2 d1 = ep[min(ei1, end - 1)];
        float w0 = (ei0 < end) ? __int_as_float(d0.y) : 0.0f;
        float w1 = (ei1 < end) ? __int_as_float(d1.y) : 0.0f;
        int2 r0 = *(const int2*)(ht + (long)d0.x * 32 + chunk * 4);
        int2 r1 = *(const int2*)(ht + (long)d1.x * 32 + chunk * 4);
        float2 f0a = __half22float2(*(__half2*)&r0.x);
        float2 f0b = __half22float2(*(__half2*)&r0.y);
        float2 f1a = __half22float2(*(__half2*)&r1.x);
        float2 f1b = __half22float2(*(__half2*)&r1.y);
        a0.x += f0a.x * w0; a0.y += f0a.y * w0; a0.z += f0b.x * w0; a0.w += f0b.y * w0;
        a1.x += f1a.x * w1; a1.y += f1a.y * w1; a1.z += f1b.x * w1; a1.w += f1b.y * w1;
    }
    a0.x += a1.x; a0.y += a1.y; a0.z += a1.z; a0.w += a1.w;
    // butterfly-reduce across eslot (lane bits 3,4,5)
    #pragma unroll
    for (int s = 8; s <= 32; s <<= 1) {
        a0.x += __shfl_xor(a0.x, s, 64);
        a0.y += __shfl_xor(a0.y, s, 64);
        a0.z += __shfl_xor(a0.z, s, 64);
        a0.w += __shfl_xor(a0.w, s, 64);
    }
    float sc = indeg_inv[wave];
    float4 b = *(const float4*)(bias + chunk * 4);
    float4 w2 = *(const float4*)(W2 + chunk * 4);
    float t = tanhf(a0.x * sc + b.x) * w2.x
            + tanhf(a0.y * sc + b.y) * w2.y
            + tanhf(a0.z * sc + b.z) * w2.z
            + tanhf(a0.w * sc + b.w) * w2.w;
    t += __shfl_xor(t, 1, 64);
    t += __shfl_xor(t, 2, 64);
    t += __shfl_xor(t, 4, 64);
    if (lane == 0) ht2[wave] = t;
}

// C=1 final aggregation: 16 lanes per node (4 nodes/wave); coalesced edge reads
__global__ void agg1_kernel(const float* __restrict__ ht2, const int* __restrict__ row_off,
                            const int2* __restrict__ ep,
                            const float* __restrict__ indeg_inv, const float* __restrict__ bias,
                            float* __restrict__ out, int N) {
    int wave = (blockIdx.x * blockDim.x + threadIdx.x) >> 6;
    int lane = threadIdx.x & 63;
    int sub = lane >> 4;         // 0..3
    int slot = lane & 15;
    int node = wave * 4 + sub;
    if (node >= N) return;
    int beg = row_off[node], end = row_off[node + 1];
    float acc = 0.0f;
    for (int e = beg + slot; e < end; e += 16) {
        int2 t = ep[e];
        acc += ht2[t.x] * __int_as_float(t.y);
    }
    #pragma unroll
    for (int s = 1; s <= 8; s <<= 1) acc += __shfl_xor(acc, s, 64);  // within 16-lane group
    if (slot == 0) out[node] = acc * indeg_inv[node] + bias[0];
}

extern "C" void kernel_launch(void* const* d_in, const int* in_sizes, int n_in,
                              void* d_out, int out_size, void* d_ws, size_t ws_size,
                              hipStream_t stream) {
    const float* b_z = (const float*)d_in[0];
    const int*   src = (const int*)d_in[1];
    const int*   dst = (const int*)d_in[2];
    const float* ew  = (const float*)d_in[3];
    const float* W0 = (const float*)d_in[5];
    const float* b0 = (const float*)d_in[6];
    const float* W1 = (const float*)d_in[7];
    const float* b1 = (const float*)d_in[8];
    const float* W2 = (const float*)d_in[9];
    const float* b2 = (const float*)d_in[10];
    float* out = (float*)d_out;

    const int N = N_NODES;
    const int E = N_EDGES;

    // workspace layout (16B-aligned segments)
    char* p = (char*)d_ws;
    int*   row_off    = (int*)p;            p += (size_t)(N + 4) * 4;
    float* outdeg_inv = (float*)p;          p += (size_t)N * 4;
    float* indeg_inv  = (float*)p;          p += (size_t)N * 4;
    int*   histD      = (int*)p;            p += (size_t)PB * NB * 4;
    int*   histS      = (int*)p;            p += (size_t)PB * NB * 4;
    int*   offD       = (int*)p;            p += (size_t)PB * NB * 4;
    int*   offS       = (int*)p;            p += (size_t)PB * NB * 4;
    int*   coarseD    = (int*)p;            p += (size_t)(NB + 4) * 4;
    int*   coarseS    = (int*)p;            p += (size_t)(NB + 4) * 4;
    int2*  edge_perm  = (int2*)p;           p += (size_t)E * 8;
    float* bufA       = (float*)p;          p += (size_t)N * 64 * 4;
    float* bufB       = (float*)p;
    // aliases with disjoint lifetimes:
    int2*   partD = (int2*)bufA;    // dead after fineD; gemm0 then writes bufA (ht fp16, 13MB)
    int*    partS = (int*)bufB;     // dead after fineS; agg64_gemm then writes bufB (ht1 fp16)
    __half* ht    = (__half*)bufA;  // N x 64 fp16, written by gemm0, read by agg64_gemm
    __half* ht1   = (__half*)bufB;  // N x 32 fp16, written by agg64_gemm, read by agg32_dot
    float*  ht2   = bufA;           // N x 1 fp32, written by agg32_dot (ht dead by then)

    // ---- atomic-free CSR build (two-level counting sort) ----
    histA_kernel<<<PB, 256, 0, stream>>>(src, dst, histD, histS);
    scanB_kernel<<<1, 256, 0, stream>>>(histD, histS, offD, offS, coarseD, coarseS);
    partC_kernel<<<PB, 256, 0, stream>>>(src, dst, ew, offD, offS, partD, partS);
    fineS_kernel<<<NB, 1024, 0, stream>>>(partS, coarseS, outdeg_inv);
    fineD_kernel<<<NB, 1024, 0, stream>>>(partD, coarseD, outdeg_inv, edge_perm, row_off, indeg_inv);

    // ---- layer 0 transform: 128 -> 64, fp16 out ----
    gemm_tile_kernel<128, 64, 4><<<N / 64, 256, 0, stream>>>(b_z, W0, ht);

    // ---- layer 0 aggregation + tanh + fused layer-1 transform (64 -> 32), fp16 out ----
    agg64_gemm_kernel<<<N / 4, 256, 0, stream>>>(ht, row_off, edge_perm, indeg_inv, b0, W1, ht1, N);

    // ---- layer 1 aggregation + tanh + fused layer-2 transform (32 -> 1) ----
    agg32_dot_kernel<<<N / 4, 256, 0, stream>>>(ht1, row_off, edge_perm, indeg_inv, b1, W2, ht2, N);

    // ---- layer 2 aggregation -> out ----
    agg1_kernel<<<N / 16, 256, 0, stream>>>(ht2, row_off, edge_perm, indeg_inv, b2, out, N);
}